// Round 4
// baseline (323.669 us; speedup 1.0000x reference)
//
#include <hip/hip_runtime.h>
#include <hip/hip_cooperative_groups.h>

namespace cg = cooperative_groups;

#define N_NODES 20000
#define N_EDGES 640000
#define N_GRAPHS 64

// pool tiling
#define NCHUNK 128
#define CHUNK_SZ 157   // 128*157 = 20096 >= 20000
#define GSPLIT 8
#define GSUB 8
#define NPOOL (NCHUNK * GSPLIT)   // 1024 virtual pool units

// graph-bucket sort: 625 tiles x 1024 edges (exact, no tail)
#define BG_TILE 1024
#define NBG 625
#define SEGCAP 48      // per-(tile,g): mean 16, Poisson tail at 48 ~ 1e-11/cell
#define GR_CAP 768     // max nodes per graph (mean 312.5, 26 sigma)
#define NSLOT4 (NBG * SEGCAP / 4)   // 7500 uint4 per graph

// ws layout (4B units), ws_size = 256 MiB:
//   Cdcol  [64][20000] f32   @ 0
//   deg    [20000] f32       @ 1,280,000
//   counts [64] f32          @ 1,300,000
//   Y      [64][256] f32     @ 1,300,064
//   glo    [65] u32 (+pad)   @ 1,316,448   graph node-range bounds
//   part   [128][64][256]    @ 1,316,528
//   bh     [625][64] u32     @ 3,413,680
//   vals   [64][625][48] u32 @ 3,453,680  (ends 5,373,680 f32 = 21.5 MB)
#define CD_OFF   0
#define DEG_OFF  1280000
#define CNT_OFF  1300000
#define Y_OFF    1300064
#define GLO_OFF  1316448
#define PART_OFF 1316528
#define BH_OFF   3413680
#define VALS_OFF 3453680

// LDS union across phases: max member (cd) = 23.3 KB -> 4 blocks/CU fits 160 KB
union ShU {
    struct {                                  // bucket: 5.7 KB
        unsigned hist[N_GRAPHS];
        unsigned base[N_GRAPHS + 1];
        unsigned lv[BG_TILE];
        unsigned char gidx[BG_TILE];
    } bk;
    struct {                                  // cd: 23.3 KB
        unsigned dh[5000];                    // 10000 u16 bins (half dst range)
        unsigned sdeg[GR_CAP];
        unsigned rcnt[4];
    } cd;
    struct {                                  // pool: 22.7 KB
        float4 sc4[CHUNK_SZ * 2];
        float sdeg[CHUNK_SZ];
        int sbatch[CHUNK_SZ];
        float4 red[2 * GSUB * 64];
    } pl;
    struct {                                  // chain: 2.5 KB
        float m[256];
        float pp[256];
        float h[128];
    } ch;
};

// ---------------- phase 1: bucket edges by g = batch[src] ----------------
__device__ __forceinline__ void phase_bucket(ShU& sh, int vb,
        const int* __restrict__ ei, const int* __restrict__ batch, float* ws) {
    unsigned* vals = (unsigned*)(ws + VALS_OFF);
    unsigned* bh   = (unsigned*)(ws + BH_OFF);
    const int t = threadIdx.x;
    if (t < N_GRAPHS) sh.bk.hist[t] = 0u;
    __syncthreads();
    const int e0 = vb * BG_TILE;              // 625*1024 = 640000 exact, no tail
    unsigned pv[4], rnk[4], gg[4];
#pragma unroll
    for (int k = 0; k < 4; ++k) {
        int i = t + k * 256;
        unsigned s = (unsigned)ei[e0 + i];
        unsigned d = (unsigned)ei[N_EDGES + e0 + i];
        unsigned g = (unsigned)batch[s];
        pv[k] = (s << 15) | d;
        gg[k] = g;
        rnk[k] = atomicAdd(&sh.bk.hist[g], 1u);
    }
    __syncthreads();
    if (t < N_GRAPHS) {                       // wave-0 shfl exclusive scan
        unsigned v = sh.bk.hist[t];
        unsigned sum = v;
#pragma unroll
        for (int off = 1; off < 64; off <<= 1) {
            unsigned u = __shfl_up(sum, off, 64);
            if (t >= off) sum += u;
        }
        sh.bk.base[t + 1] = sum;
        if (t == 0) sh.bk.base[0] = 0u;
        bh[vb * N_GRAPHS + t] = (v > SEGCAP) ? SEGCAP : v;
    }
    __syncthreads();
    if (t < N_GRAPHS) {                       // fill gidx runs
        unsigned b0_ = sh.bk.base[t], b1_ = sh.bk.base[t + 1];
        for (unsigned i = b0_; i < b1_; ++i) sh.bk.gidx[i] = (unsigned char)t;
    }
#pragma unroll
    for (int k = 0; k < 4; ++k)
        sh.bk.lv[sh.bk.base[gg[k]] + rnk[k]] = pv[k];
    __syncthreads();
    for (int i = t; i < BG_TILE; i += 256) {  // contiguous per-g runs, coalesced
        unsigned g = sh.bk.gidx[i];
        unsigned slot = (unsigned)i - sh.bk.base[g];
        if (slot < SEGCAP)
            vals[((size_t)g * NBG + vb) * SEGCAP + slot] = sh.bk.lv[i];
    }
    __syncthreads();                          // protect LDS reuse next vb
}

// Y zero (block 0) + graph node-range binary searches (block 1, parallel over g)
__device__ __forceinline__ void phase_init(int bid, const int* __restrict__ batch, float* ws) {
    const int t = threadIdx.x;
    if (bid == 0) {
        float4* y4 = (float4*)(ws + Y_OFF);
        for (int i = t; i < 64 * 64; i += 256) y4[i] = make_float4(0.f, 0.f, 0.f, 0.f);
    } else if (bid == 1) {
        if (t <= N_GRAPHS) {
            int lo = 0, hi = N_NODES;
            while (lo < hi) { int m = (lo + hi) >> 1; if (batch[m] < t) lo = m + 1; else hi = m; }
            ((unsigned*)(ws + GLO_OFF))[t] = (unsigned)lo;
        }
    }
}

// ---------------- phase 2: per-graph histograms (vb = g*2 + half) ----------------
__device__ __forceinline__ void phase_cd(ShU& sh, int vb, float* ws) {
    const unsigned* vals = (const unsigned*)(ws + VALS_OFF);
    const unsigned* bh   = (const unsigned*)(ws + BH_OFF);
    const unsigned* glo  = (const unsigned*)(ws + GLO_OFF);
    float* Cdcol  = ws + CD_OFF;
    float* deg    = ws + DEG_OFF;
    float* counts = ws + CNT_OFF;
    const int t = threadIdx.x;
    const int g = vb >> 1, h = vb & 1;
    for (int i = t; i < 5000; i += 256) sh.cd.dh[i] = 0u;
    if (h == 0) for (int i = t; i < GR_CAP; i += 256) sh.cd.sdeg[i] = 0u;
    __syncthreads();
    const int lo = (int)glo[g];
    const int hi = (int)glo[g + 1];
    const int dbase = h * 10000;
    const uint4* v4 = (const uint4*)(vals + (size_t)g * NBG * SEGCAP);
    const unsigned* bhg = bh + g;
    for (int i = t; i < NSLOT4; i += 256) {
        uint4 v = *(v4 + i);
        unsigned w = (unsigned)i * 4u;
        unsigned seg = w / 48u;               // compiler emits magic-mul
        unsigned local = w - seg * 48u;
        unsigned c = bhg[(size_t)seg * N_GRAPHS];
#define CD_ONE(VX, L)                                                            \
        if ((L) < c) {                                                           \
            int rd_ = (int)((VX) & 0x7FFFu) - dbase;                             \
            if ((unsigned)rd_ < 10000u)                                          \
                atomicAdd(&sh.cd.dh[rd_ >> 1], 1u << ((rd_ & 1) * 16));          \
            if (h == 0) {                                                        \
                int rs_ = (int)((VX) >> 15) - lo;                                \
                if ((unsigned)rs_ < (unsigned)GR_CAP) atomicAdd(&sh.cd.sdeg[rs_], 1u); \
            }                                                                    \
        }
        CD_ONE(v.x, local + 0u)
        CD_ONE(v.y, local + 1u)
        CD_ONE(v.z, local + 2u)
        CD_ONE(v.w, local + 3u)
#undef CD_ONE
    }
    __syncthreads();
    float2* outc = (float2*)(Cdcol + (size_t)g * N_NODES + dbase);
    for (int wd = t; wd < 5000; wd += 256) {
        unsigned v = sh.cd.dh[wd];
        outc[wd] = make_float2((float)(v & 0xFFFFu), (float)(v >> 16));
    }
    if (h == 0) {
        const int range = hi - lo;
        for (int i = t; i < range; i += 256) deg[lo + i] = (float)sh.cd.sdeg[i];
        unsigned s = 0;                       // counts[g]: parallel reduce of bh column
        for (int seg = t; seg < NBG; seg += 256) s += bhg[(size_t)seg * N_GRAPHS];
#pragma unroll
        for (int off = 32; off; off >>= 1) s += __shfl_down(s, off, 64);
        if ((t & 63) == 0) sh.cd.rcnt[t >> 6] = s;
        __syncthreads();
        if (t == 0) counts[g] = (float)(sh.cd.rcnt[0] + sh.cd.rcnt[1] + sh.cd.rcnt[2] + sh.cd.rcnt[3]);
    }
    __syncthreads();
}

#define FMA8(C0, C1, XV)                                          \
    acc[0].x = fmaf(C0.x, XV.x, acc[0].x); acc[0].y = fmaf(C0.x, XV.y, acc[0].y); \
    acc[0].z = fmaf(C0.x, XV.z, acc[0].z); acc[0].w = fmaf(C0.x, XV.w, acc[0].w); \
    acc[1].x = fmaf(C0.y, XV.x, acc[1].x); acc[1].y = fmaf(C0.y, XV.y, acc[1].y); \
    acc[1].z = fmaf(C0.y, XV.z, acc[1].z); acc[1].w = fmaf(C0.y, XV.w, acc[1].w); \
    acc[2].x = fmaf(C0.z, XV.x, acc[2].x); acc[2].y = fmaf(C0.z, XV.y, acc[2].y); \
    acc[2].z = fmaf(C0.z, XV.z, acc[2].z); acc[2].w = fmaf(C0.z, XV.w, acc[2].w); \
    acc[3].x = fmaf(C0.w, XV.x, acc[3].x); acc[3].y = fmaf(C0.w, XV.y, acc[3].y); \
    acc[3].z = fmaf(C0.w, XV.z, acc[3].z); acc[3].w = fmaf(C0.w, XV.w, acc[3].w); \
    acc[4].x = fmaf(C1.x, XV.x, acc[4].x); acc[4].y = fmaf(C1.x, XV.y, acc[4].y); \
    acc[4].z = fmaf(C1.x, XV.z, acc[4].z); acc[4].w = fmaf(C1.x, XV.w, acc[4].w); \
    acc[5].x = fmaf(C1.y, XV.x, acc[5].x); acc[5].y = fmaf(C1.y, XV.y, acc[5].y); \
    acc[5].z = fmaf(C1.y, XV.z, acc[5].z); acc[5].w = fmaf(C1.y, XV.w, acc[5].w); \
    acc[6].x = fmaf(C1.z, XV.x, acc[6].x); acc[6].y = fmaf(C1.z, XV.y, acc[6].y); \
    acc[6].z = fmaf(C1.z, XV.z, acc[6].z); acc[6].w = fmaf(C1.z, XV.w, acc[6].w); \
    acc[7].x = fmaf(C1.w, XV.x, acc[7].x); acc[7].y = fmaf(C1.w, XV.y, acc[7].y); \
    acc[7].z = fmaf(C1.w, XV.z, acc[7].z); acc[7].w = fmaf(C1.w, XV.w, acc[7].w);

// ---------------- phase 3: pool (vb = b + 128*j) ----------------
__device__ __forceinline__ void phase_pool(ShU& sh, int vb,
        const float* __restrict__ x, const int* __restrict__ batch, float* ws) {
    const float* Cdcol = ws + CD_OFF;
    const float* deg   = ws + DEG_OFF;
    float* Y    = ws + Y_OFF;
    float* part = ws + PART_OFF;
    const int t = threadIdx.x;
    const int fg = t & 63;
    const int p  = t >> 6;
    const int b = vb & 127;
    const int j = vb >> 7;
    const int n0 = b * CHUNK_SZ;
    const int cnt = (n0 + CHUNK_SZ <= N_NODES) ? CHUNK_SZ : (N_NODES - n0);

    float* sc = (float*)sh.pl.sc4;
    const float* cbase = Cdcol + (size_t)(j * GSUB) * N_NODES + n0;
#pragma unroll
    for (int k = 0; k < GSUB; ++k)
        for (int i = t; i < cnt; i += 256)
            sc[i * GSUB + k] = cbase[(size_t)k * N_NODES + i];
    if (j == 0) {
        for (int i = t; i < cnt; i += 256) {
            sh.pl.sdeg[i] = deg[n0 + i];
            sh.pl.sbatch[i] = batch[n0 + i];
        }
    }
    __syncthreads();

    const float4* xp = (const float4*)x + (size_t)n0 * 64 + fg;
#define XL(I) xp[(size_t)(I) * 64]
    float4 acc[GSUB];
#pragma unroll
    for (int k = 0; k < GSUB; ++k) acc[k] = make_float4(0.f, 0.f, 0.f, 0.f);

    if (j == 0) {
        float4 accs = make_float4(0.f, 0.f, 0.f, 0.f);
        int gprev = (p < cnt) ? sh.pl.sbatch[p] : 0;
        int i = p;
        float4 xn = make_float4(0.f, 0.f, 0.f, 0.f);
        if (i < cnt) xn = XL(i);
        for (; i < cnt; i += 4) {
            float4 xv = xn;
            if (i + 4 < cnt) xn = XL(i + 4);
            int g = sh.pl.sbatch[i];
            if (g != gprev) {
                float* yr = Y + gprev * 256 + fg * 4;
                atomicAdd(yr + 0, accs.x); atomicAdd(yr + 1, accs.y);
                atomicAdd(yr + 2, accs.z); atomicAdd(yr + 3, accs.w);
                accs = make_float4(0.f, 0.f, 0.f, 0.f);
                gprev = g;
            }
            float dg = sh.pl.sdeg[i];
            accs.x = fmaf(dg, xv.x, accs.x); accs.y = fmaf(dg, xv.y, accs.y);
            accs.z = fmaf(dg, xv.z, accs.z); accs.w = fmaf(dg, xv.w, accs.w);
            float4 c0 = sh.pl.sc4[i * 2], c1 = sh.pl.sc4[i * 2 + 1];
            FMA8(c0, c1, xv)
        }
        if (p < cnt) {
            float* yr = Y + gprev * 256 + fg * 4;
            atomicAdd(yr + 0, accs.x); atomicAdd(yr + 1, accs.y);
            atomicAdd(yr + 2, accs.z); atomicAdd(yr + 3, accs.w);
        }
    } else {
        int i = p;
        float4 xa, xb, xc, xd;
        if (i      < cnt) xa = XL(i);
        if (i + 4  < cnt) xb = XL(i + 4);
        if (i + 8  < cnt) xc = XL(i + 8);
        if (i + 12 < cnt) xd = XL(i + 12);
        for (; i + 12 < cnt; i += 16) {
            float4 y0 = xa, y1 = xb, y2 = xc, y3 = xd;
            if (i + 16 < cnt) xa = XL(i + 16);
            if (i + 20 < cnt) xb = XL(i + 20);
            if (i + 24 < cnt) xc = XL(i + 24);
            if (i + 28 < cnt) xd = XL(i + 28);
            { float4 c0 = sh.pl.sc4[i * 2],       c1 = sh.pl.sc4[i * 2 + 1];       FMA8(c0, c1, y0) }
            { float4 c0 = sh.pl.sc4[(i + 4) * 2], c1 = sh.pl.sc4[(i + 4) * 2 + 1]; FMA8(c0, c1, y1) }
            { float4 c0 = sh.pl.sc4[(i + 8) * 2], c1 = sh.pl.sc4[(i + 8) * 2 + 1]; FMA8(c0, c1, y2) }
            { float4 c0 = sh.pl.sc4[(i + 12) * 2],c1 = sh.pl.sc4[(i + 12) * 2 + 1];FMA8(c0, c1, y3) }
        }
        for (; i < cnt; i += 4) {
            float4 xv = XL(i);
            float4 c0 = sh.pl.sc4[i * 2], c1 = sh.pl.sc4[i * 2 + 1];
            FMA8(c0, c1, xv)
        }
    }
#undef XL

    // cross-phase reduce 4 -> 2 -> 1
    if (p >= 2) {
#pragma unroll
        for (int k = 0; k < GSUB; ++k) sh.pl.red[(p - 2) * (GSUB * 64) + k * 64 + fg] = acc[k];
    }
    __syncthreads();
    if (p < 2) {
#pragma unroll
        for (int k = 0; k < GSUB; ++k) {
            float4 v = sh.pl.red[p * (GSUB * 64) + k * 64 + fg];
            acc[k].x += v.x; acc[k].y += v.y; acc[k].z += v.z; acc[k].w += v.w;
        }
    }
    __syncthreads();
    if (p == 1) {
#pragma unroll
        for (int k = 0; k < GSUB; ++k) sh.pl.red[k * 64 + fg] = acc[k];
    }
    __syncthreads();
    if (p == 0) {
        float4* part4 = (float4*)part;
#pragma unroll
        for (int k = 0; k < GSUB; ++k) {
            float4 v = sh.pl.red[k * 64 + fg];
            acc[k].x += v.x; acc[k].y += v.y; acc[k].z += v.z; acc[k].w += v.w;
            part4[(size_t)(b * 64 + j * GSUB + k) * 64 + fg] = acc[k];
        }
    }
    __syncthreads();                          // protect LDS reuse next vb
}

// ---------------- phase 4: fused reduce + 3-layer chain (vb = r) ----------------
__device__ __forceinline__ void phase_chain(ShU& sh, int vb, float* ws,
        const float* __restrict__ W0, const float* __restrict__ b0,
        const float* __restrict__ W1, const float* __restrict__ b1,
        const float* __restrict__ W2, const float* __restrict__ b2,
        float* __restrict__ out) {
    const float* Y      = ws + Y_OFF;
    const float* part   = ws + PART_OFF;
    const float* counts = ws + CNT_OFF;
    const int r = vb;
    const int t = threadIdx.x;
    const int g = r & 63;
    const int half = (r >= 64) ? 128 : 0;
    const int tt = t & 127;
    const int ks = t >> 7;

    float c = counts[g];
    float inv = 1.0f / fmaxf(c, 1.0f);
    float beta = c * inv;

    if (r < 64) {
        sh.ch.m[t] = Y[g * 256 + t] * inv;
    } else {
        float s = 0.0f;
#pragma unroll 8
        for (int bb = 0; bb < NCHUNK; ++bb) s += part[(size_t)(bb * 64 + g) * 256 + t];
        sh.ch.m[t] = s * inv;
    }
    __syncthreads();

    {   // layer 1: 256 -> 128, k split 128/128
        float s = 0.0f;
        const float* w = W0 + (ks * 128) * 128 + tt;
        const float* mm = sh.ch.m + ks * 128;
#pragma unroll 8
        for (int k = 0; k < 128; ++k) s = fmaf(mm[k], w[k * 128], s);
        sh.ch.pp[t] = s;
    }
    __syncthreads();
    if (t < 128) {
        float s1 = sh.ch.pp[t] + sh.ch.pp[t + 128] + beta * b0[t];
        out[g * 768 + 0 + half + t] = s1;
        sh.ch.h[t] = s1;
    }
    __syncthreads();

    {   // layer 2: 128 -> 128, k split 64/64
        float s = 0.0f;
        const float* w = W1 + (ks * 64) * 128 + tt;
        const float* hh = sh.ch.h + ks * 64;
#pragma unroll 8
        for (int k = 0; k < 64; ++k) s = fmaf(hh[k], w[k * 128], s);
        sh.ch.pp[t] = s;
    }
    __syncthreads();
    float s2 = 0.0f;
    if (t < 128) {
        s2 = sh.ch.pp[t] + sh.ch.pp[t + 128] + beta * b1[t];
        out[g * 768 + 256 + half + t] = s2;
    }
    __syncthreads();
    if (t < 128) sh.ch.h[t] = s2;
    __syncthreads();

    {   // layer 3: 128 -> 128, k split 64/64
        float s = 0.0f;
        const float* w = W2 + (ks * 64) * 128 + tt;
        const float* hh = sh.ch.h + ks * 64;
#pragma unroll 8
        for (int k = 0; k < 64; ++k) s = fmaf(hh[k], w[k * 128], s);
        sh.ch.pp[t] = s;
    }
    __syncthreads();
    if (t < 128) {
        float s3 = sh.ch.pp[t] + sh.ch.pp[t + 128] + beta * b2[t];
        out[g * 768 + 512 + half + t] = s3;
    }
    __syncthreads();
}

// ---------------- fused cooperative kernel ----------------
__global__ __launch_bounds__(256, 4) void fused_k(
        const float* __restrict__ x, const int* __restrict__ ei, const int* __restrict__ batch,
        const float* __restrict__ W0, const float* __restrict__ b0,
        const float* __restrict__ W1, const float* __restrict__ b1,
        const float* __restrict__ W2, const float* __restrict__ b2,
        float* __restrict__ out, float* ws) {
    __shared__ ShU sh;
    cg::grid_group grid = cg::this_grid();
    for (int vb = blockIdx.x; vb < NBG; vb += gridDim.x)
        phase_bucket(sh, vb, ei, batch, ws);
    phase_init(blockIdx.x, batch, ws);
    grid.sync();
    for (int vb = blockIdx.x; vb < 2 * N_GRAPHS; vb += gridDim.x)
        phase_cd(sh, vb, ws);
    grid.sync();
    for (int vb = blockIdx.x; vb < NPOOL; vb += gridDim.x)
        phase_pool(sh, vb, x, batch, ws);
    grid.sync();
    for (int vb = blockIdx.x; vb < 128; vb += gridDim.x)
        phase_chain(sh, vb, ws, W0, b0, W1, b1, W2, b2, out);
}

// ---------------- fallback: same phases as 4 plain dispatches ----------------
__global__ __launch_bounds__(256) void p1_k(const int* __restrict__ ei,
                                            const int* __restrict__ batch, float* ws) {
    __shared__ ShU sh;
    phase_bucket(sh, blockIdx.x, ei, batch, ws);
    phase_init(blockIdx.x, batch, ws);
}
__global__ __launch_bounds__(256) void p2_k(float* ws) {
    __shared__ ShU sh;
    phase_cd(sh, blockIdx.x, ws);
}
__global__ __launch_bounds__(256) void p3_k(const float* __restrict__ x,
                                            const int* __restrict__ batch, float* ws) {
    __shared__ ShU sh;
    phase_pool(sh, blockIdx.x, x, batch, ws);
}
__global__ __launch_bounds__(256) void p4_k(float* ws,
        const float* __restrict__ W0, const float* __restrict__ b0,
        const float* __restrict__ W1, const float* __restrict__ b1,
        const float* __restrict__ W2, const float* __restrict__ b2,
        float* __restrict__ out) {
    __shared__ ShU sh;
    phase_chain(sh, blockIdx.x, ws, W0, b0, W1, b1, W2, b2, out);
}

extern "C" void kernel_launch(void* const* d_in, const int* in_sizes, int n_in,
                              void* d_out, int out_size, void* d_ws, size_t ws_size,
                              hipStream_t stream) {
    const float* x     = (const float*)d_in[0];
    const int*   ei    = (const int*)d_in[1];
    const int*   batch = (const int*)d_in[2];
    const float* W0    = (const float*)d_in[3];
    const float* b0    = (const float*)d_in[4];
    const float* W1    = (const float*)d_in[5];
    const float* b1    = (const float*)d_in[6];
    const float* W2    = (const float*)d_in[7];
    const float* b2    = (const float*)d_in[8];
    float* out = (float*)d_out;
    float* ws  = (float*)d_ws;

    void* kargs[] = {(void*)&x, (void*)&ei, (void*)&batch,
                     (void*)&W0, (void*)&b0, (void*)&W1, (void*)&b1, (void*)&W2, (void*)&b2,
                     (void*)&out, (void*)&ws};

    int nb = 0;
    hipError_t qerr = hipOccupancyMaxActiveBlocksPerMultiprocessor(&nb, (const void*)fused_k, 256, 0);
    hipError_t lerr = hipErrorUnknown;
    if (qerr == hipSuccess && nb > 0) {
        int grid = nb * 256;                  // 256 CUs, co-residency guaranteed by query
        if (grid > 1024) grid = 1024;
        lerr = hipLaunchCooperativeKernel((void*)fused_k, dim3(grid), dim3(256), kargs, 0, stream);
    }
    if (lerr != hipSuccess) {                 // safe fallback: identical math, 4 dispatches
        p1_k<<<NBG, 256, 0, stream>>>(ei, batch, ws);
        p2_k<<<2 * N_GRAPHS, 256, 0, stream>>>(ws);
        p3_k<<<NPOOL, 256, 0, stream>>>(x, batch, ws);
        p4_k<<<128, 256, 0, stream>>>(ws, W0, b0, W1, b1, W2, b2, out);
    }
}

// Round 5
// 288.518 us; speedup vs baseline: 1.1218x; 1.1218x over previous
//
#include <hip/hip_runtime.h>

#define N_NODES 20000
#define N_EDGES 640000
#define N_GRAPHS 64

// pool tiling
#define NCHUNK 128
#define CHUNK_SZ 157   // 128*157 = 20096 >= 20000
#define GSPLIT 8
#define GSUB 8
#define NPOOL (NCHUNK * GSPLIT)   // 1024 pool producer blocks

// graph-bucket sort (r3-proven geometry)
#define BG_TILE 2048
#define NBG 313        // ceil(640000/2048)
#define SEGCAP 80
#define GR_CAP 768
#define NSLOT4 (NBG * SEGCAP / 4)   // 6260 uint4 per graph
#define NCD 128        // cd consumer units: (g, dst-half)

// ws layout (4B units), ws_size = 256 MiB:
//   Cdcol  [64][20000] f32   @ 0
//   deg    [20000] f32       @ 1,280,000
//   counts [64] f32          @ 1,300,000
//   Y      [64][256] f32     @ 1,300,064  (zeroed by k12 blk0)
//   part   [128][64][256]    @ 1,316,448
//   bh     [313][64] u32     @ 3,413,600
//   vals   [64][313][80] u32 @ 3,433,632  (ends 5,036,192)
//   fl1    [313] u32 (+pad)  @ 5,036,192  bucket completion flags
//   fl3    [1024] u32        @ 5,036,512  pool completion flags
#define CD_OFF   0
#define DEG_OFF  1280000
#define CNT_OFF  1300000
#define Y_OFF    1300064
#define PART_OFF 1316448
#define BH_OFF   3413600
#define VALS_OFF 3433632
#define FL1_OFF  5036192
#define FL3_OFF  5036512

// per-index magic: poison (repeated-byte patterns) cannot match 313/1024
// distinct index-dependent words
#define MAGIC1(i) (0x5AB10000u | (unsigned)(i))
#define MAGIC3(i) (0x5AB30000u | (unsigned)(i))

// =================== kernel 1: bucket producers + cd consumers ===================
union Sh12 {
    struct {                                  // bucket: 10.6 KB
        unsigned hist[N_GRAPHS];
        unsigned base[N_GRAPHS + 1];
        unsigned lv[BG_TILE];
        unsigned char gidx[BG_TILE];
    } bk;
    struct {                                  // cd: 24.4 KB
        unsigned dh[5000];                    // 10000 u16 bins (one dst-half)
        unsigned sdeg[GR_CAP];
        unsigned scnt[NBG];
        unsigned rc[8];
        int lohi[2];
    } cd;
};

__global__ __launch_bounds__(512) void k12_k(const int* __restrict__ ei,
                                             const int* __restrict__ batch,
                                             float* ws) {
    __shared__ Sh12 sh;
    unsigned* vals = (unsigned*)(ws + VALS_OFF);
    unsigned* bh   = (unsigned*)(ws + BH_OFF);
    unsigned* fl1  = (unsigned*)(ws + FL1_OFF);
    const int t = threadIdx.x;
    const int vb = blockIdx.x;

    if (vb < NBG) {
        // ---------- bucket tile vb (r3 logic, 512 threads) ----------
        if (t < N_GRAPHS) sh.bk.hist[t] = 0u;
        __syncthreads();
        const int e0 = vb * BG_TILE;
        const int ecnt = (e0 + BG_TILE <= N_EDGES) ? BG_TILE : (N_EDGES - e0);
        unsigned pv[4], rnk[4], gg[4];
#pragma unroll
        for (int k = 0; k < 4; ++k) {
            int i = t + k * 512;
            if (i < ecnt) {
                unsigned s = (unsigned)ei[e0 + i];
                unsigned d = (unsigned)ei[N_EDGES + e0 + i];
                unsigned g = (unsigned)batch[s];
                pv[k] = (s << 15) | d;
                gg[k] = g;
                rnk[k] = atomicAdd(&sh.bk.hist[g], 1u);
            } else {
                gg[k] = 0xFFFFFFFFu;
            }
        }
        __syncthreads();
        if (t < N_GRAPHS) {                    // wave-0 shfl exclusive scan
            unsigned v = sh.bk.hist[t];
            unsigned sum = v;
#pragma unroll
            for (int off = 1; off < 64; off <<= 1) {
                unsigned u = __shfl_up(sum, off, 64);
                if (t >= off) sum += u;
            }
            sh.bk.base[t + 1] = sum;
            if (t == 0) sh.bk.base[0] = 0u;
            bh[vb * N_GRAPHS + t] = (v > SEGCAP) ? SEGCAP : v;
        }
        __syncthreads();
        if (t < N_GRAPHS) {
            unsigned b0_ = sh.bk.base[t], b1_ = sh.bk.base[t + 1];
            for (unsigned i = b0_; i < b1_; ++i) sh.bk.gidx[i] = (unsigned char)t;
        }
#pragma unroll
        for (int k = 0; k < 4; ++k) {
            if (gg[k] != 0xFFFFFFFFu) sh.bk.lv[sh.bk.base[gg[k]] + rnk[k]] = pv[k];
        }
        __syncthreads();
        for (int i = t; i < ecnt; i += 512) {  // coalesced per-g runs
            unsigned g = sh.bk.gidx[i];
            unsigned slot = (unsigned)i - sh.bk.base[g];
            if (slot < SEGCAP)
                vals[((size_t)g * NBG + vb) * SEGCAP + slot] = sh.bk.lv[i];
        }
        if (vb == 0) {                         // zero pool's atomic target
            float4* y4 = (float4*)(ws + Y_OFF);
            for (int i = t; i < 64 * 64; i += 512) y4[i] = make_float4(0.f, 0.f, 0.f, 0.f);
        }
        __syncthreads();                       // drains all vmem (barrier semantics)
        if (t == 0) {
            __threadfence();                   // L2 writeback: publish vals/bh/Y
            __hip_atomic_store(&fl1[vb], MAGIC1(vb), __ATOMIC_RELEASE, __HIP_MEMORY_SCOPE_AGENT);
        }
    } else {
        // ---------- cd consumer: unit c = (g, dst-half) ----------
        const int c = vb - NBG;
        const int g = c >> 1, h = c & 1;
        for (int i = t; i < 5000; i += 512) sh.cd.dh[i] = 0u;
        if (h == 0) for (int i = t; i < GR_CAP; i += 512) sh.cd.sdeg[i] = 0u;
        if (t < 2) {                           // binary searches overlap the wait
            int lo = 0, hi = N_NODES, tg = g + t;
            while (lo < hi) { int m = (lo + hi) >> 1; if (batch[m] < tg) lo = m + 1; else hi = m; }
            sh.cd.lohi[t] = lo;
        }
        for (int f = t; f < NBG; f += 512) {   // wait for all bucket tiles
            while (__hip_atomic_load(&fl1[f], __ATOMIC_ACQUIRE, __HIP_MEMORY_SCOPE_AGENT) != MAGIC1(f))
                __builtin_amdgcn_s_sleep(16);
        }
        __syncthreads();
        __threadfence();                       // acquire: invalidate stale lines
        for (int i = t; i < NBG; i += 512) sh.cd.scnt[i] = bh[i * N_GRAPHS + g];
        __syncthreads();

        const int lo = sh.cd.lohi[0];
        const int dbase = h * 10000;
        const uint4* v4 = (const uint4*)(vals + (size_t)g * NBG * SEGCAP);
        for (int i = t; i < NSLOT4; i += 512) {
            uint4 v = v4[i];
            unsigned w = (unsigned)i * 4u;
            unsigned seg = (unsigned)(((unsigned long long)w * 53687092ull) >> 32);  // w/80
            unsigned local = w - seg * 80u;
            unsigned cn = sh.cd.scnt[seg];
#define CD_ONE(VX, L)                                                            \
            if ((L) < cn) {                                                      \
                int rd_ = (int)((VX) & 0x7FFFu) - dbase;                         \
                if ((unsigned)rd_ < 10000u)                                      \
                    atomicAdd(&sh.cd.dh[rd_ >> 1], 1u << ((rd_ & 1) * 16));      \
                if (h == 0) {                                                    \
                    int rs_ = (int)((VX) >> 15) - lo;                            \
                    if ((unsigned)rs_ < (unsigned)GR_CAP) atomicAdd(&sh.cd.sdeg[rs_], 1u); \
                }                                                                \
            }
            CD_ONE(v.x, local + 0u)
            CD_ONE(v.y, local + 1u)
            CD_ONE(v.z, local + 2u)
            CD_ONE(v.w, local + 3u)
#undef CD_ONE
        }
        __syncthreads();
        float2* outc = (float2*)(ws + CD_OFF + (size_t)g * N_NODES + dbase);
        for (int wd = t; wd < 5000; wd += 512) {
            unsigned v = sh.cd.dh[wd];
            outc[wd] = make_float2((float)(v & 0xFFFFu), (float)(v >> 16));
        }
        if (h == 0) {
            const int hi2 = sh.cd.lohi[1];
            const int range = hi2 - lo;
            for (int i = t; i < range; i += 512) (ws + DEG_OFF)[lo + i] = (float)sh.cd.sdeg[i];
            unsigned s = 0;                    // counts[g]: parallel reduce of scnt
            for (int i = t; i < NBG; i += 512) s += sh.cd.scnt[i];
#pragma unroll
            for (int off = 32; off; off >>= 1) s += __shfl_down(s, off, 64);
            if ((t & 63) == 0) sh.cd.rc[t >> 6] = s;
            __syncthreads();
            if (t == 0) {
                unsigned tot = 0;
#pragma unroll
                for (int i2 = 0; i2 < 8; ++i2) tot += sh.cd.rc[i2];
                (ws + CNT_OFF)[g] = (float)tot;
            }
        }
    }
}

// =================== kernel 2: pool producers + chain consumers ===================
#define FMA8(C0, C1, XV)                                          \
    acc[0].x = fmaf(C0.x, XV.x, acc[0].x); acc[0].y = fmaf(C0.x, XV.y, acc[0].y); \
    acc[0].z = fmaf(C0.x, XV.z, acc[0].z); acc[0].w = fmaf(C0.x, XV.w, acc[0].w); \
    acc[1].x = fmaf(C0.y, XV.x, acc[1].x); acc[1].y = fmaf(C0.y, XV.y, acc[1].y); \
    acc[1].z = fmaf(C0.y, XV.z, acc[1].z); acc[1].w = fmaf(C0.y, XV.w, acc[1].w); \
    acc[2].x = fmaf(C0.z, XV.x, acc[2].x); acc[2].y = fmaf(C0.z, XV.y, acc[2].y); \
    acc[2].z = fmaf(C0.z, XV.z, acc[2].z); acc[2].w = fmaf(C0.z, XV.w, acc[2].w); \
    acc[3].x = fmaf(C0.w, XV.x, acc[3].x); acc[3].y = fmaf(C0.w, XV.y, acc[3].y); \
    acc[3].z = fmaf(C0.w, XV.z, acc[3].z); acc[3].w = fmaf(C0.w, XV.w, acc[3].w); \
    acc[4].x = fmaf(C1.x, XV.x, acc[4].x); acc[4].y = fmaf(C1.x, XV.y, acc[4].y); \
    acc[4].z = fmaf(C1.x, XV.z, acc[4].z); acc[4].w = fmaf(C1.x, XV.w, acc[4].w); \
    acc[5].x = fmaf(C1.y, XV.x, acc[5].x); acc[5].y = fmaf(C1.y, XV.y, acc[5].y); \
    acc[5].z = fmaf(C1.y, XV.z, acc[5].z); acc[5].w = fmaf(C1.y, XV.w, acc[5].w); \
    acc[6].x = fmaf(C1.z, XV.x, acc[6].x); acc[6].y = fmaf(C1.z, XV.y, acc[6].y); \
    acc[6].z = fmaf(C1.z, XV.z, acc[6].z); acc[6].w = fmaf(C1.z, XV.w, acc[6].w); \
    acc[7].x = fmaf(C1.w, XV.x, acc[7].x); acc[7].y = fmaf(C1.w, XV.y, acc[7].y); \
    acc[7].z = fmaf(C1.w, XV.z, acc[7].z); acc[7].w = fmaf(C1.w, XV.w, acc[7].w);

union Sh3 {
    struct {                                  // pool: 22.7 KB
        float4 sc4[CHUNK_SZ * 2];
        float sdeg[CHUNK_SZ];
        int sbatch[CHUNK_SZ];
        float4 red[2 * GSUB * 64];
    } pl;
    struct {                                  // chain: 2.5 KB
        float m[256];
        float pp[256];
        float h[128];
    } ch;
};

__global__ __launch_bounds__(256) void k3_k(const float* __restrict__ x,
                                            const int* __restrict__ batch,
                                            const float* __restrict__ W0, const float* __restrict__ b0,
                                            const float* __restrict__ W1, const float* __restrict__ b1,
                                            const float* __restrict__ W2, const float* __restrict__ b2,
                                            float* __restrict__ out, float* ws) {
    __shared__ Sh3 sh;
    unsigned* fl3 = (unsigned*)(ws + FL3_OFF);
    const int t = threadIdx.x;
    const int vb = blockIdx.x;

    if (vb < NPOOL) {
        // ---------- pool producer (r3 logic verbatim) ----------
        const float* Cdcol = ws + CD_OFF;
        const float* deg   = ws + DEG_OFF;
        float* Y    = ws + Y_OFF;
        float* part = ws + PART_OFF;
        const int fg = t & 63;
        const int p  = t >> 6;
        const int b = vb & 127;               // same chunk's 8 splits: same XCD mod 8
        const int j = vb >> 7;
        const int n0 = b * CHUNK_SZ;
        const int cnt = (n0 + CHUNK_SZ <= N_NODES) ? CHUNK_SZ : (N_NODES - n0);

        float* sc = (float*)sh.pl.sc4;
        const float* cbase = Cdcol + (size_t)(j * GSUB) * N_NODES + n0;
#pragma unroll
        for (int k = 0; k < GSUB; ++k)
            for (int i = t; i < cnt; i += 256)
                sc[i * GSUB + k] = cbase[(size_t)k * N_NODES + i];
        if (j == 0) {
            for (int i = t; i < cnt; i += 256) {
                sh.pl.sdeg[i] = deg[n0 + i];
                sh.pl.sbatch[i] = batch[n0 + i];
            }
        }
        __syncthreads();

        const float4* xp = (const float4*)x + (size_t)n0 * 64 + fg;
#define XL(I) xp[(size_t)(I) * 64]
        float4 acc[GSUB];
#pragma unroll
        for (int k = 0; k < GSUB; ++k) acc[k] = make_float4(0.f, 0.f, 0.f, 0.f);

        if (j == 0) {
            float4 accs = make_float4(0.f, 0.f, 0.f, 0.f);
            int gprev = (p < cnt) ? sh.pl.sbatch[p] : 0;
            int i = p;
            float4 xn = make_float4(0.f, 0.f, 0.f, 0.f);
            if (i < cnt) xn = XL(i);
            for (; i < cnt; i += 4) {
                float4 xv = xn;
                if (i + 4 < cnt) xn = XL(i + 4);
                int g = sh.pl.sbatch[i];
                if (g != gprev) {
                    float* yr = Y + gprev * 256 + fg * 4;
                    atomicAdd(yr + 0, accs.x); atomicAdd(yr + 1, accs.y);
                    atomicAdd(yr + 2, accs.z); atomicAdd(yr + 3, accs.w);
                    accs = make_float4(0.f, 0.f, 0.f, 0.f);
                    gprev = g;
                }
                float dg = sh.pl.sdeg[i];
                accs.x = fmaf(dg, xv.x, accs.x); accs.y = fmaf(dg, xv.y, accs.y);
                accs.z = fmaf(dg, xv.z, accs.z); accs.w = fmaf(dg, xv.w, accs.w);
                float4 c0 = sh.pl.sc4[i * 2], c1 = sh.pl.sc4[i * 2 + 1];
                FMA8(c0, c1, xv)
            }
            if (p < cnt) {
                float* yr = Y + gprev * 256 + fg * 4;
                atomicAdd(yr + 0, accs.x); atomicAdd(yr + 1, accs.y);
                atomicAdd(yr + 2, accs.z); atomicAdd(yr + 3, accs.w);
            }
        } else {
            int i = p;
            float4 xa, xb, xc, xd;
            if (i      < cnt) xa = XL(i);
            if (i + 4  < cnt) xb = XL(i + 4);
            if (i + 8  < cnt) xc = XL(i + 8);
            if (i + 12 < cnt) xd = XL(i + 12);
            for (; i + 12 < cnt; i += 16) {
                float4 y0 = xa, y1 = xb, y2 = xc, y3 = xd;
                if (i + 16 < cnt) xa = XL(i + 16);
                if (i + 20 < cnt) xb = XL(i + 20);
                if (i + 24 < cnt) xc = XL(i + 24);
                if (i + 28 < cnt) xd = XL(i + 28);
                { float4 c0 = sh.pl.sc4[i * 2],        c1 = sh.pl.sc4[i * 2 + 1];        FMA8(c0, c1, y0) }
                { float4 c0 = sh.pl.sc4[(i + 4) * 2],  c1 = sh.pl.sc4[(i + 4) * 2 + 1];  FMA8(c0, c1, y1) }
                { float4 c0 = sh.pl.sc4[(i + 8) * 2],  c1 = sh.pl.sc4[(i + 8) * 2 + 1];  FMA8(c0, c1, y2) }
                { float4 c0 = sh.pl.sc4[(i + 12) * 2], c1 = sh.pl.sc4[(i + 12) * 2 + 1]; FMA8(c0, c1, y3) }
            }
            for (; i < cnt; i += 4) {
                float4 xv = XL(i);
                float4 c0 = sh.pl.sc4[i * 2], c1 = sh.pl.sc4[i * 2 + 1];
                FMA8(c0, c1, xv)
            }
        }
#undef XL

        if (p >= 2) {
#pragma unroll
            for (int k = 0; k < GSUB; ++k) sh.pl.red[(p - 2) * (GSUB * 64) + k * 64 + fg] = acc[k];
        }
        __syncthreads();
        if (p < 2) {
#pragma unroll
            for (int k = 0; k < GSUB; ++k) {
                float4 v = sh.pl.red[p * (GSUB * 64) + k * 64 + fg];
                acc[k].x += v.x; acc[k].y += v.y; acc[k].z += v.z; acc[k].w += v.w;
            }
        }
        __syncthreads();
        if (p == 1) {
#pragma unroll
            for (int k = 0; k < GSUB; ++k) sh.pl.red[k * 64 + fg] = acc[k];
        }
        __syncthreads();
        if (p == 0) {
            float4* part4 = (float4*)part;
#pragma unroll
            for (int k = 0; k < GSUB; ++k) {
                float4 v = sh.pl.red[k * 64 + fg];
                acc[k].x += v.x; acc[k].y += v.y; acc[k].z += v.z; acc[k].w += v.w;
                part4[(size_t)(b * 64 + j * GSUB + k) * 64 + fg] = acc[k];
            }
        }
        __syncthreads();                       // drain part stores / Y atomics
        if (t == 0) {
            __threadfence();                   // publish part
            __hip_atomic_store(&fl3[vb], MAGIC3(vb), __ATOMIC_RELEASE, __HIP_MEMORY_SCOPE_AGENT);
        }
    } else {
        // ---------- chain consumer: unit r = vb - NPOOL ----------
        const int r = vb - NPOOL;
        for (int f = t; f < NPOOL; f += 256) { // wait for all pool blocks
            while (__hip_atomic_load(&fl3[f], __ATOMIC_ACQUIRE, __HIP_MEMORY_SCOPE_AGENT) != MAGIC3(f))
                __builtin_amdgcn_s_sleep(32);
        }
        __syncthreads();
        __threadfence();                       // acquire: invalidate stale lines

        const float* Y      = ws + Y_OFF;
        const float* part   = ws + PART_OFF;
        const float* counts = ws + CNT_OFF;
        const int g = r & 63;
        const int half = (r >= 64) ? 128 : 0;
        const int tt = t & 127;
        const int ks = t >> 7;

        float c = counts[g];
        float inv = 1.0f / fmaxf(c, 1.0f);
        float beta = c * inv;

        if (r < 64) {
            sh.ch.m[t] = Y[g * 256 + t] * inv;
        } else {
            float s = 0.0f;
#pragma unroll 8
            for (int bb = 0; bb < NCHUNK; ++bb) s += part[(size_t)(bb * 64 + g) * 256 + t];
            sh.ch.m[t] = s * inv;
        }
        __syncthreads();

        {   // layer 1: 256 -> 128, k split 128/128
            float s = 0.0f;
            const float* w = W0 + (ks * 128) * 128 + tt;
            const float* mm = sh.ch.m + ks * 128;
#pragma unroll 8
            for (int k = 0; k < 128; ++k) s = fmaf(mm[k], w[k * 128], s);
            sh.ch.pp[t] = s;
        }
        __syncthreads();
        if (t < 128) {
            float s1 = sh.ch.pp[t] + sh.ch.pp[t + 128] + beta * b0[t];
            out[g * 768 + 0 + half + t] = s1;
            sh.ch.h[t] = s1;
        }
        __syncthreads();

        {   // layer 2: 128 -> 128, k split 64/64
            float s = 0.0f;
            const float* w = W1 + (ks * 64) * 128 + tt;
            const float* hh = sh.ch.h + ks * 64;
#pragma unroll 8
            for (int k = 0; k < 64; ++k) s = fmaf(hh[k], w[k * 128], s);
            sh.ch.pp[t] = s;
        }
        __syncthreads();
        float s2 = 0.0f;
        if (t < 128) {
            s2 = sh.ch.pp[t] + sh.ch.pp[t + 128] + beta * b1[t];
            out[g * 768 + 256 + half + t] = s2;
        }
        __syncthreads();
        if (t < 128) sh.ch.h[t] = s2;
        __syncthreads();

        {   // layer 3: 128 -> 128, k split 64/64
            float s = 0.0f;
            const float* w = W2 + (ks * 64) * 128 + tt;
            const float* hh = sh.ch.h + ks * 64;
#pragma unroll 8
            for (int k = 0; k < 64; ++k) s = fmaf(hh[k], w[k * 128], s);
            sh.ch.pp[t] = s;
        }
        __syncthreads();
        if (t < 128) {
            float s3 = sh.ch.pp[t] + sh.ch.pp[t + 128] + beta * b2[t];
            out[g * 768 + 512 + half + t] = s3;
        }
    }
}

extern "C" void kernel_launch(void* const* d_in, const int* in_sizes, int n_in,
                              void* d_out, int out_size, void* d_ws, size_t ws_size,
                              hipStream_t stream) {
    const float* x     = (const float*)d_in[0];
    const int*   ei    = (const int*)d_in[1];
    const int*   batch = (const int*)d_in[2];
    const float* W0    = (const float*)d_in[3];
    const float* b0    = (const float*)d_in[4];
    const float* W1    = (const float*)d_in[5];
    const float* b1    = (const float*)d_in[6];
    const float* W2    = (const float*)d_in[7];
    const float* b2    = (const float*)d_in[8];
    float* out = (float*)d_out;
    float* ws  = (float*)d_ws;

    k12_k<<<NBG + NCD, 512, 0, stream>>>(ei, batch, ws);
    k3_k<<<NPOOL + 128, 256, 0, stream>>>(x, batch, W0, b0, W1, b1, W2, b2, out, ws);
}

// Round 6
// 145.714 us; speedup vs baseline: 2.2213x; 1.9800x over previous
//
#include <hip/hip_runtime.h>

#define N_NODES 20000
#define N_EDGES 640000
#define N_GRAPHS 64

// pool tiling: one block per chunk, all 64 graphs; 8 waves x 8 graphs each
#define NCHUNK 250
#define CHUNK_SZ 80    // 250*80 = 20000 exact, no tail
#define GSUB 8

// graph-bucket sort (r3-proven geometry)
#define BG_TILE 2048
#define NBG 313        // ceil(640000/2048)
#define SEGCAP 80
#define GR_CAP 768
#define NSLOT4 (NBG * SEGCAP / 4)   // 6260 uint4 per graph

// ws layout (4B units), ws_size = 256 MiB:
//   Cdcol  [64][20000] f32   @ 0
//   deg    [20000] f32       @ 1,280,000
//   counts [64] f32          @ 1,300,000
//   Y      [64][256] f32     @ 1,300,064  (zeroed by bucket blk0)
//   part   [250][64][256]    @ 1,316,448  (ends 5,412,448)
//   bh     [313][64] u32     @ 5,412,448
//   vals   [64][313][80] u32 @ 5,432,480  (ends 7,035,040)
#define CD_OFF   0
#define DEG_OFF  1280000
#define CNT_OFF  1300000
#define Y_OFF    1300064
#define PART_OFF 1316448
#define BH_OFF   5412448
#define VALS_OFF 5432480

// bucket edges by g = batch[src]: LDS rank + wave-0 shfl prefix-sum, reorder
// tile in LDS by g, write vals in contiguous per-g runs (r3 verbatim).
__global__ __launch_bounds__(512) void bucket_g_k(const int* __restrict__ ei,
                                                  const int* __restrict__ batch,
                                                  unsigned* __restrict__ vals,
                                                  unsigned* __restrict__ bh,
                                                  float* __restrict__ Y) {
    __shared__ unsigned hist[N_GRAPHS];
    __shared__ unsigned base[N_GRAPHS + 1];
    __shared__ unsigned lv[BG_TILE];          // 8 KB reorder tile
    __shared__ unsigned char gidx[BG_TILE];   // 2 KB: output index -> graph
    const int t = threadIdx.x;
    const int blk = blockIdx.x;
    if (t < N_GRAPHS) hist[t] = 0u;
    __syncthreads();

    const int e0 = blk * BG_TILE;
    const int ecnt = (e0 + BG_TILE <= N_EDGES) ? BG_TILE : (N_EDGES - e0);
    unsigned pv[4], rnk[4], gg[4];
#pragma unroll
    for (int k = 0; k < 4; ++k) {
        int i = t + k * 512;
        if (i < ecnt) {
            unsigned s = (unsigned)ei[e0 + i];
            unsigned d = (unsigned)ei[N_EDGES + e0 + i];
            unsigned g = (unsigned)batch[s];
            pv[k] = (s << 15) | d;
            gg[k] = g;
            rnk[k] = atomicAdd(&hist[g], 1u);
        } else {
            gg[k] = 0xFFFFFFFFu;
        }
    }
    __syncthreads();
    if (t < N_GRAPHS) {                        // wave-0 shfl exclusive scan
        unsigned v = hist[t];
        unsigned sum = v;
#pragma unroll
        for (int off = 1; off < 64; off <<= 1) {
            unsigned u = __shfl_up(sum, off, 64);
            if (t >= off) sum += u;
        }
        base[t + 1] = sum;
        if (t == 0) base[0] = 0u;
        bh[blk * N_GRAPHS + t] = (v > SEGCAP) ? SEGCAP : v;
    }
    __syncthreads();
    if (t < N_GRAPHS) {                        // fill gidx runs
        unsigned b0_ = base[t], b1_ = base[t + 1];
        for (unsigned i = b0_; i < b1_; ++i) gidx[i] = (unsigned char)t;
    }
#pragma unroll
    for (int k = 0; k < 4; ++k) {
        if (gg[k] != 0xFFFFFFFFu) lv[base[gg[k]] + rnk[k]] = pv[k];
    }
    __syncthreads();
    for (int i = t; i < ecnt; i += 512) {      // coalesced per-g runs
        unsigned g = gidx[i];
        unsigned slot = (unsigned)i - base[g];
        if (slot < SEGCAP)
            vals[((size_t)g * NBG + blk) * SEGCAP + slot] = lv[i];
    }
    if (blk == 0) {                            // zero pool's atomic target
        float4* y4 = (float4*)Y;
        for (int i = t; i < 64 * 64; i += 512) y4[i] = make_float4(0.f, 0.f, 0.f, 0.f);
    }
}

// single-pass per-graph histogram: one block per g, 1024 threads, full-range
// u16 LDS hist (40 KB); vals read exactly once (r3 verbatim).
__global__ __launch_bounds__(1024) void cd_col_k(const unsigned* __restrict__ vals,
                                                 const unsigned* __restrict__ bh,
                                                 const int* __restrict__ batch,
                                                 float* __restrict__ Cdcol,
                                                 float* __restrict__ deg,
                                                 float* __restrict__ counts) {
    __shared__ unsigned scnt[NBG];
    __shared__ unsigned dh[10000];         // 40 KB: 20000 dst counts, u16 halves
    __shared__ unsigned sdeg[GR_CAP];      // 3 KB
    __shared__ int s_lo, s_hi;
    const int t = threadIdx.x;
    const int g = blockIdx.x;

    for (int i = t; i < 10000; i += 1024) dh[i] = 0u;
    if (t < NBG) scnt[t] = bh[t * N_GRAPHS + g];
    if (t < GR_CAP) sdeg[t] = 0u;
    if (t == 0) {
        int lo = 0, hi = N_NODES;                    // lower_bound(g)
        while (lo < hi) { int m = (lo + hi) >> 1; if (batch[m] < g) lo = m + 1; else hi = m; }
        s_lo = lo;
        int lo2 = lo; hi = N_NODES;                  // lower_bound(g+1)
        while (lo2 < hi) { int m = (lo2 + hi) >> 1; if (batch[m] < g + 1) lo2 = m + 1; else hi = m; }
        s_hi = lo2;
    }
    __syncthreads();
    const int lo = s_lo;

    const uint4* v4 = (const uint4*)(vals + (size_t)g * NBG * SEGCAP);
    for (int i = t; i < NSLOT4; i += 1024) {
        uint4 v = *(v4 + i);
        unsigned w = (unsigned)i * 4u;
        unsigned seg = (unsigned)(((unsigned long long)w * 53687092ull) >> 32);  // w/80 exact
        unsigned local = w - seg * 80u;
        unsigned c = scnt[seg];
#define CD_ONE(VX, L)                                                            \
        if ((L) < c) {                                                           \
            unsigned rd_ = (VX) & 0x7FFFu;                                       \
            atomicAdd(&dh[rd_ >> 1], 1u << ((rd_ & 1) * 16));                    \
            int rs_ = (int)((VX) >> 15) - lo;                                    \
            if ((unsigned)rs_ < (unsigned)GR_CAP) atomicAdd(&sdeg[rs_], 1u);     \
        }
        CD_ONE(v.x, local + 0u)
        CD_ONE(v.y, local + 1u)
        CD_ONE(v.z, local + 2u)
        CD_ONE(v.w, local + 3u)
#undef CD_ONE
    }
    __syncthreads();

    float2* outc = (float2*)(Cdcol + (size_t)g * N_NODES);
    for (int w = t; w < 10000; w += 1024) {
        unsigned v = dh[w];
        outc[w] = make_float2((float)(v & 0xFFFFu), (float)(v >> 16));
    }
    {
        const int range = s_hi - lo;
        for (int i = t; i < range; i += 1024) deg[lo + i] = (float)sdeg[i];
        if (t == 0) {
            unsigned tot = 0;
            for (int i = 0; i < NBG; ++i) tot += scnt[i];
            counts[g] = (float)tot;
        }
    }
}

#define FMA8(C0, C1, XV)                                          \
    acc[0].x = fmaf(C0.x, XV.x, acc[0].x); acc[0].y = fmaf(C0.x, XV.y, acc[0].y); \
    acc[0].z = fmaf(C0.x, XV.z, acc[0].z); acc[0].w = fmaf(C0.x, XV.w, acc[0].w); \
    acc[1].x = fmaf(C0.y, XV.x, acc[1].x); acc[1].y = fmaf(C0.y, XV.y, acc[1].y); \
    acc[1].z = fmaf(C0.y, XV.z, acc[1].z); acc[1].w = fmaf(C0.y, XV.w, acc[1].w); \
    acc[2].x = fmaf(C0.z, XV.x, acc[2].x); acc[2].y = fmaf(C0.z, XV.y, acc[2].y); \
    acc[2].z = fmaf(C0.z, XV.z, acc[2].z); acc[2].w = fmaf(C0.z, XV.w, acc[2].w); \
    acc[3].x = fmaf(C0.w, XV.x, acc[3].x); acc[3].y = fmaf(C0.w, XV.y, acc[3].y); \
    acc[3].z = fmaf(C0.w, XV.z, acc[3].z); acc[3].w = fmaf(C0.w, XV.w, acc[3].w); \
    acc[4].x = fmaf(C1.x, XV.x, acc[4].x); acc[4].y = fmaf(C1.x, XV.y, acc[4].y); \
    acc[4].z = fmaf(C1.x, XV.z, acc[4].z); acc[4].w = fmaf(C1.x, XV.w, acc[4].w); \
    acc[5].x = fmaf(C1.y, XV.x, acc[5].x); acc[5].y = fmaf(C1.y, XV.y, acc[5].y); \
    acc[5].z = fmaf(C1.y, XV.z, acc[5].z); acc[5].w = fmaf(C1.y, XV.w, acc[5].w); \
    acc[6].x = fmaf(C1.z, XV.x, acc[6].x); acc[6].y = fmaf(C1.z, XV.y, acc[6].y); \
    acc[6].z = fmaf(C1.z, XV.z, acc[6].z); acc[6].w = fmaf(C1.z, XV.w, acc[6].w); \
    acc[7].x = fmaf(C1.w, XV.x, acc[7].x); acc[7].y = fmaf(C1.w, XV.y, acc[7].y); \
    acc[7].z = fmaf(C1.w, XV.z, acc[7].z); acc[7].w = fmaf(C1.w, XV.w, acc[7].w);

// pool v2: block = chunk (250 x 80 nodes), 512 threads = 8 waves, wave p owns
// graphs [8p, 8p+8). Cd values are node-level -> whole-wave broadcast LDS reads
// (conflict-free); x read once with cross-wave L1/L2 reuse; NO cross-wave
// reduce (waves own disjoint graphs). src path handled by the owning wave.
__global__ __launch_bounds__(512) void pool_k(const float* __restrict__ x,
                                              const int* __restrict__ batch,
                                              const float* __restrict__ Cdcol,
                                              const float* __restrict__ deg,
                                              float* __restrict__ Y,
                                              float* __restrict__ part) {
    __shared__ float4 sc4[CHUNK_SZ * 17];     // 21.8 KB: [node][16 f4 + 1 pad]
    __shared__ float sdeg[CHUNK_SZ];
    __shared__ int   sbatch[CHUNK_SZ];

    const int t = threadIdx.x;
    const int fg = t & 63;                    // float4 feature group (lane)
    const int p  = t >> 6;                    // wave id 0..7 -> graphs 8p..8p+7
    const int b  = blockIdx.x;
    const int n0 = b * CHUNK_SZ;

    // stage Cd columns transposed: scf[i*68 + g] = Cdcol[g][n0+i]
    float* scf = (float*)sc4;
    for (int e = t; e < N_GRAPHS * CHUNK_SZ; e += 512) {
        unsigned g = (unsigned)e / (unsigned)CHUNK_SZ;
        unsigned i = (unsigned)e - g * (unsigned)CHUNK_SZ;
        scf[i * 68u + g] = Cdcol[(size_t)g * N_NODES + n0 + i];
    }
    if (t < CHUNK_SZ) {
        sdeg[t] = deg[n0 + t];
        sbatch[t] = batch[n0 + t];
    }
    __syncthreads();

    const float4* xp = (const float4*)x + (size_t)n0 * 64 + fg;
    float4 acc[GSUB];
#pragma unroll
    for (int k = 0; k < GSUB; ++k) acc[k] = make_float4(0.f, 0.f, 0.f, 0.f);
    float4 accs = make_float4(0.f, 0.f, 0.f, 0.f);
    int gprev = -1;

    // 2-deep x prefetch (covers L2 latency at 2 waves/SIMD)
    float4 xn0 = xp[0];
    float4 xn1 = xp[64];
    for (int i = 0; i < CHUNK_SZ; ++i) {
        float4 xv = xn0;
        xn0 = xn1;
        if (i + 2 < CHUNK_SZ) xn1 = xp[(size_t)(i + 2) * 64];
        float4 c0 = sc4[i * 17 + 2 * p];      // graphs 8p..8p+3 (broadcast)
        float4 c1 = sc4[i * 17 + 2 * p + 1];  // graphs 8p+4..8p+7
        int g = sbatch[i];                    // node-level -> wave-uniform
        if ((g >> 3) == p) {                  // owning wave does the src path
            if (g != gprev) {
                if (gprev >= 0) {
                    float* yr = Y + gprev * 256 + fg * 4;
                    atomicAdd(yr + 0, accs.x); atomicAdd(yr + 1, accs.y);
                    atomicAdd(yr + 2, accs.z); atomicAdd(yr + 3, accs.w);
                }
                accs = make_float4(0.f, 0.f, 0.f, 0.f);
                gprev = g;
            }
            float dg = sdeg[i];
            accs.x = fmaf(dg, xv.x, accs.x); accs.y = fmaf(dg, xv.y, accs.y);
            accs.z = fmaf(dg, xv.z, accs.z); accs.w = fmaf(dg, xv.w, accs.w);
        }
        FMA8(c0, c1, xv)
    }
    if (gprev >= 0) {
        float* yr = Y + gprev * 256 + fg * 4;
        atomicAdd(yr + 0, accs.x); atomicAdd(yr + 1, accs.y);
        atomicAdd(yr + 2, accs.z); atomicAdd(yr + 3, accs.w);
    }

    float4* part4 = (float4*)part;
#pragma unroll
    for (int k = 0; k < GSUB; ++k)
        part4[(size_t)(b * 64 + p * GSUB + k) * 64 + fg] = acc[k];
}

// fused reduce + chain (r3 structure, NCHUNK=250 slabs): 128 blocks x 256 thr.
__global__ __launch_bounds__(256) void chain2_k(const float* __restrict__ Y,
                                                const float* __restrict__ part,
                                                const float* __restrict__ counts,
                                                const float* __restrict__ W0, const float* __restrict__ b0,
                                                const float* __restrict__ W1, const float* __restrict__ b1,
                                                const float* __restrict__ W2, const float* __restrict__ b2,
                                                float* __restrict__ out) {
    __shared__ float m[256];
    __shared__ float pp[256];   // split-k partials
    __shared__ float h[128];
    const int r = blockIdx.x;
    const int t = threadIdx.x;
    const int g = r & 63;
    const int half = (r >= 64) ? 128 : 0;
    const int tt = t & 127;
    const int ks = t >> 7;      // k-split id: 0 or 1

    float c = counts[g];
    float inv = 1.0f / fmaxf(c, 1.0f);
    float beta = c * inv;

    if (r < 64) {
        m[t] = Y[g * 256 + t] * inv;
    } else {
        float s = 0.0f;
#pragma unroll 5
        for (int bb = 0; bb < NCHUNK; ++bb) s += part[(size_t)(bb * 64 + g) * 256 + t];
        m[t] = s * inv;
    }
    __syncthreads();

    // layer 1: m(256) @ W0(256x128) -> 128, k split 128/128
    {
        float s = 0.0f;
        const float* w = W0 + (ks * 128) * 128 + tt;
        const float* mm = m + ks * 128;
#pragma unroll 8
        for (int k = 0; k < 128; ++k) s = fmaf(mm[k], w[k * 128], s);
        pp[t] = s;
    }
    __syncthreads();
    if (t < 128) {
        float s1 = pp[t] + pp[t + 128] + beta * b0[t];
        out[g * 768 + 0 + half + t] = s1;
        h[t] = s1;
    }
    __syncthreads();

    // layer 2: h(128) @ W1(128x128) -> 128, k split 64/64
    {
        float s = 0.0f;
        const float* w = W1 + (ks * 64) * 128 + tt;
        const float* hh = h + ks * 64;
#pragma unroll 8
        for (int k = 0; k < 64; ++k) s = fmaf(hh[k], w[k * 128], s);
        pp[t] = s;
    }
    __syncthreads();
    float s2 = 0.0f;
    if (t < 128) {
        s2 = pp[t] + pp[t + 128] + beta * b1[t];
        out[g * 768 + 256 + half + t] = s2;
    }
    __syncthreads();
    if (t < 128) h[t] = s2;
    __syncthreads();

    // layer 3: h(128) @ W2(128x128) -> 128, k split 64/64
    {
        float s = 0.0f;
        const float* w = W2 + (ks * 64) * 128 + tt;
        const float* hh = h + ks * 64;
#pragma unroll 8
        for (int k = 0; k < 64; ++k) s = fmaf(hh[k], w[k * 128], s);
        pp[t] = s;
    }
    __syncthreads();
    if (t < 128) {
        float s3 = pp[t] + pp[t + 128] + beta * b2[t];
        out[g * 768 + 512 + half + t] = s3;
    }
}

extern "C" void kernel_launch(void* const* d_in, const int* in_sizes, int n_in,
                              void* d_out, int out_size, void* d_ws, size_t ws_size,
                              hipStream_t stream) {
    const float* x     = (const float*)d_in[0];
    const int*   ei    = (const int*)d_in[1];
    const int*   batch = (const int*)d_in[2];
    const float* W0    = (const float*)d_in[3];
    const float* b0    = (const float*)d_in[4];
    const float* W1    = (const float*)d_in[5];
    const float* b1    = (const float*)d_in[6];
    const float* W2    = (const float*)d_in[7];
    const float* b2    = (const float*)d_in[8];
    float* out = (float*)d_out;

    float*    ws     = (float*)d_ws;
    float*    Cdcol  = ws + CD_OFF;
    float*    deg    = ws + DEG_OFF;
    float*    counts = ws + CNT_OFF;
    float*    Y      = ws + Y_OFF;
    float*    part   = ws + PART_OFF;
    unsigned* bh     = (unsigned*)(ws + BH_OFF);
    unsigned* vals   = (unsigned*)(ws + VALS_OFF);

    bucket_g_k<<<NBG, 512, 0, stream>>>(ei, batch, vals, bh, Y);
    cd_col_k<<<N_GRAPHS, 1024, 0, stream>>>(vals, bh, batch, Cdcol, deg, counts);
    pool_k<<<NCHUNK, 512, 0, stream>>>(x, batch, Cdcol, deg, Y, part);
    chain2_k<<<128, 256, 0, stream>>>(Y, part, counts, W0, b0, W1, b1, W2, b2, out);
}

// Round 7
// 119.954 us; speedup vs baseline: 2.6983x; 1.2147x over previous
//
#include <hip/hip_runtime.h>

#define N_NODES 20000
#define N_EDGES 640000
#define N_GRAPHS 64

// pool tiling (r3-proven)
#define NCHUNK 128
#define CHUNK_SZ 157   // 128*157 = 20096 >= 20000
#define GSPLIT 8       // graph-dim split: 8 blocks of 8 graphs each
#define GSUB 8

// graph-bucket sort (r3-proven geometry)
#define BG_TILE 2048
#define NBG 313        // ceil(640000/2048)
#define SEGCAP 80
#define GR_CAP 768
#define NSLOT4 (NBG * SEGCAP / 4)   // 6260 uint4 per graph

// ws layout (4B units), ws_size = 256 MiB:
//   Cdcol  [64][20000] f32     at 0
//   deg    [20000] f32         at 1,280,000
//   counts [64] f32            at 1,300,000
//   Y      [64][256] f32       at 1,300,064  (zeroed by bucket tail block)
//   part   [128][64][256] f32  at 1,316,448
//   bh     [313][64] u32       at 3,413,600
//   vals   [64][313][80] u32   at 3,433,632  (ends 5,036,192)
//   glo    [65] u32            at 5,036,192  graph node-range bounds
#define CD_OFF      0
#define DEG_OFF     1280000
#define CNT_OFF     1300000
#define Y_OFF       1300064
#define PART_OFF    1316448
#define BH_OFF      3413600
#define VALS_OFF    3433632
#define GLO_OFF     5036192

// bucket edges by g = batch[src] (r3 verbatim, 512 thr). Extra tail block
// (blk==NBG) does the 65 graph-range binary searches in parallel + Y zero —
// off the tile critical path (all 314 blocks co-resident).
__global__ __launch_bounds__(512) void bucket_g_k(const int* __restrict__ ei,
                                                  const int* __restrict__ batch,
                                                  unsigned* __restrict__ vals,
                                                  unsigned* __restrict__ bh,
                                                  float* __restrict__ Y,
                                                  unsigned* __restrict__ glo) {
    __shared__ unsigned hist[N_GRAPHS];
    __shared__ unsigned base[N_GRAPHS + 1];
    __shared__ unsigned lv[BG_TILE];          // 8 KB reorder tile
    __shared__ unsigned char gidx[BG_TILE];   // 2 KB: output index -> graph
    const int t = threadIdx.x;
    const int blk = blockIdx.x;

    if (blk == NBG) {                          // tail block: glo + Y zero
        if (t < N_GRAPHS + 1) {                // 65 parallel binary searches
            int lo = 0, hi = N_NODES;
            while (lo < hi) { int m = (lo + hi) >> 1; if (batch[m] < t) lo = m + 1; else hi = m; }
            glo[t] = (unsigned)lo;
        }
        float4* y4 = (float4*)Y;
        for (int i = t; i < 64 * 64; i += 512) y4[i] = make_float4(0.f, 0.f, 0.f, 0.f);
        return;
    }

    if (t < N_GRAPHS) hist[t] = 0u;
    __syncthreads();

    const int e0 = blk * BG_TILE;
    const int ecnt = (e0 + BG_TILE <= N_EDGES) ? BG_TILE : (N_EDGES - e0);
    unsigned pv[4], rnk[4], gg[4];
#pragma unroll
    for (int k = 0; k < 4; ++k) {
        int i = t + k * 512;
        if (i < ecnt) {
            unsigned s = (unsigned)ei[e0 + i];
            unsigned d = (unsigned)ei[N_EDGES + e0 + i];
            unsigned g = (unsigned)batch[s];
            pv[k] = (s << 15) | d;
            gg[k] = g;
            rnk[k] = atomicAdd(&hist[g], 1u);
        } else {
            gg[k] = 0xFFFFFFFFu;
        }
    }
    __syncthreads();
    if (t < N_GRAPHS) {                        // wave-0 shfl exclusive scan
        unsigned v = hist[t];
        unsigned sum = v;
#pragma unroll
        for (int off = 1; off < 64; off <<= 1) {
            unsigned u = __shfl_up(sum, off, 64);
            if (t >= off) sum += u;
        }
        base[t + 1] = sum;
        if (t == 0) base[0] = 0u;
        bh[blk * N_GRAPHS + t] = (v > SEGCAP) ? SEGCAP : v;
    }
    __syncthreads();
    if (t < N_GRAPHS) {                        // fill gidx runs
        unsigned b0_ = base[t], b1_ = base[t + 1];
        for (unsigned i = b0_; i < b1_; ++i) gidx[i] = (unsigned char)t;
    }
#pragma unroll
    for (int k = 0; k < 4; ++k) {
        if (gg[k] != 0xFFFFFFFFu) lv[base[gg[k]] + rnk[k]] = pv[k];
    }
    __syncthreads();
    for (int i = t; i < ecnt; i += 512) {      // coalesced per-g runs
        unsigned g = gidx[i];
        unsigned slot = (unsigned)i - base[g];
        if (slot < SEGCAP)
            vals[((size_t)g * NBG + blk) * SEGCAP + slot] = lv[i];
    }
}

// cd v3: 128 blocks = (dst-half h = bid>>6, graph g = bid&63); blocks g and
// g+64 are 64 apart -> same XCD (64%8==0) -> vals L2-shared. 1024 threads,
// 20 KB u16 hist per half. No serial searches (glo precomputed); counts via
// grid-stride + shfl parallel reduce. h0: dst-half-0 + counts. h1: dst-half-1
// + sdeg/deg. Work per block ~halved vs r3's single-pass.
__global__ __launch_bounds__(1024) void cd_col_k(const unsigned* __restrict__ vals,
                                                 const unsigned* __restrict__ bh,
                                                 const unsigned* __restrict__ glo,
                                                 float* __restrict__ Cdcol,
                                                 float* __restrict__ deg,
                                                 float* __restrict__ counts) {
    __shared__ unsigned scnt[NBG];
    __shared__ unsigned dh[5000];          // 20 KB: 10000 dst bins, u16 halves
    __shared__ unsigned sdeg[GR_CAP];      // 3 KB (h==1 only)
    __shared__ unsigned rc[16];
    const int t = threadIdx.x;
    const int g = blockIdx.x & 63;
    const int h = blockIdx.x >> 6;
    const int dbase = h * 10000;

    for (int i = t; i < 5000; i += 1024) dh[i] = 0u;
    if (h) { if (t < GR_CAP) sdeg[t] = 0u; }
    if (t < NBG) scnt[t] = bh[t * N_GRAPHS + g];
    __syncthreads();
    const int lo = (int)glo[g];
    const int hi = (int)glo[g + 1];

    const uint4* v4 = (const uint4*)(vals + (size_t)g * NBG * SEGCAP);
    for (int i = t; i < NSLOT4; i += 1024) {
        uint4 v = *(v4 + i);
        unsigned w = (unsigned)i * 4u;
        unsigned seg = (unsigned)(((unsigned long long)w * 53687092ull) >> 32);  // w/80 exact
        unsigned local = w - seg * 80u;
        unsigned c = scnt[seg];
#define CD_ONE(VX, L)                                                            \
        if ((L) < c) {                                                           \
            int rd_ = (int)((VX) & 0x7FFFu) - dbase;                             \
            if ((unsigned)rd_ < 10000u)                                          \
                atomicAdd(&dh[rd_ >> 1], 1u << ((rd_ & 1) * 16));                \
            if (h) {                                                             \
                int rs_ = (int)((VX) >> 15) - lo;                                \
                if ((unsigned)rs_ < (unsigned)GR_CAP) atomicAdd(&sdeg[rs_], 1u); \
            }                                                                    \
        }
        CD_ONE(v.x, local + 0u)
        CD_ONE(v.y, local + 1u)
        CD_ONE(v.z, local + 2u)
        CD_ONE(v.w, local + 3u)
#undef CD_ONE
    }
    __syncthreads();

    float2* outc = (float2*)(Cdcol + (size_t)g * N_NODES + dbase);
    for (int w = t; w < 5000; w += 1024) {
        unsigned v = dh[w];
        outc[w] = make_float2((float)(v & 0xFFFFu), (float)(v >> 16));
    }
    if (h) {
        const int range = hi - lo;
        for (int i = t; i < range; i += 1024) deg[lo + i] = (float)sdeg[i];
    } else {
        unsigned s = 0;                        // counts[g]: parallel reduce of bh column
        for (int i = t; i < NBG; i += 1024) s += scnt[i];
#pragma unroll
        for (int off = 32; off; off >>= 1) s += __shfl_down(s, off, 64);
        if ((t & 63) == 0) rc[t >> 6] = s;
        __syncthreads();
        if (t == 0) {
            unsigned tot = 0;
#pragma unroll
            for (int i = 0; i < 16; ++i) tot += rc[i];
            counts[g] = (float)tot;
        }
    }
}

#define FMA8(C0, C1, XV)                                          \
    acc[0].x = fmaf(C0.x, XV.x, acc[0].x); acc[0].y = fmaf(C0.x, XV.y, acc[0].y); \
    acc[0].z = fmaf(C0.x, XV.z, acc[0].z); acc[0].w = fmaf(C0.x, XV.w, acc[0].w); \
    acc[1].x = fmaf(C0.y, XV.x, acc[1].x); acc[1].y = fmaf(C0.y, XV.y, acc[1].y); \
    acc[1].z = fmaf(C0.y, XV.z, acc[1].z); acc[1].w = fmaf(C0.y, XV.w, acc[1].w); \
    acc[2].x = fmaf(C0.z, XV.x, acc[2].x); acc[2].y = fmaf(C0.z, XV.y, acc[2].y); \
    acc[2].z = fmaf(C0.z, XV.z, acc[2].z); acc[2].w = fmaf(C0.z, XV.w, acc[2].w); \
    acc[3].x = fmaf(C0.w, XV.x, acc[3].x); acc[3].y = fmaf(C0.w, XV.y, acc[3].y); \
    acc[3].z = fmaf(C0.w, XV.z, acc[3].z); acc[3].w = fmaf(C0.w, XV.w, acc[3].w); \
    acc[4].x = fmaf(C1.x, XV.x, acc[4].x); acc[4].y = fmaf(C1.x, XV.y, acc[4].y); \
    acc[4].z = fmaf(C1.x, XV.z, acc[4].z); acc[4].w = fmaf(C1.x, XV.w, acc[4].w); \
    acc[5].x = fmaf(C1.y, XV.x, acc[5].x); acc[5].y = fmaf(C1.y, XV.y, acc[5].y); \
    acc[5].z = fmaf(C1.y, XV.z, acc[5].z); acc[5].w = fmaf(C1.y, XV.w, acc[5].w); \
    acc[6].x = fmaf(C1.z, XV.x, acc[6].x); acc[6].y = fmaf(C1.z, XV.y, acc[6].y); \
    acc[6].z = fmaf(C1.z, XV.z, acc[6].z); acc[6].w = fmaf(C1.z, XV.w, acc[6].w); \
    acc[7].x = fmaf(C1.w, XV.x, acc[7].x); acc[7].y = fmaf(C1.w, XV.y, acc[7].y); \
    acc[7].z = fmaf(C1.w, XV.z, acc[7].z); acc[7].w = fmaf(C1.w, XV.w, acc[7].w);

// pool (r3 verbatim): block = (chunk b, split j of 8 graphs). 4 waves = 4 node
// phases; dst loop unrolled x4 with 4 prefetches in flight; tree reduce.
__global__ __launch_bounds__(256) void pool_k(const float* __restrict__ x,
                                              const int* __restrict__ batch,
                                              const float* __restrict__ Cdcol,
                                              const float* __restrict__ deg,
                                              float* __restrict__ Y,
                                              float* __restrict__ part) {
    __shared__ float4 sc4[CHUNK_SZ * 2];      // 5 KB: [node][2] float4 (GSUB=8)
    __shared__ float sdeg[CHUNK_SZ];
    __shared__ int   sbatch[CHUNK_SZ];
    __shared__ float4 red[2 * GSUB * 64];     // 16 KB cross-phase reduce

    const int t = threadIdx.x;
    const int fg = t & 63;                    // float4 feature group
    const int p  = t >> 6;                    // phase == wave id
    const int b = blockIdx.x & 127;           // same chunk's 8 splits: same XCD mod 8
    const int j = blockIdx.x >> 7;
    const int n0 = b * CHUNK_SZ;
    const int cnt = (n0 + CHUNK_SZ <= N_NODES) ? CHUNK_SZ : (N_NODES - n0);

    // transpose-stage 8 Cd columns into [node][8] LDS layout
    float* sc = (float*)sc4;
    const float* cbase = Cdcol + (size_t)(j * GSUB) * N_NODES + n0;
#pragma unroll
    for (int k = 0; k < GSUB; ++k)
        for (int i = t; i < cnt; i += 256)
            sc[i * GSUB + k] = cbase[(size_t)k * N_NODES + i];
    if (j == 0) {
        for (int i = t; i < cnt; i += 256) {
            sdeg[i] = deg[n0 + i];
            sbatch[i] = batch[n0 + i];
        }
    }
    __syncthreads();

    const float4* xp = (const float4*)x + (size_t)n0 * 64 + fg;
#define XL(I) xp[(size_t)(I) * 64]
    float4 acc[GSUB];
#pragma unroll
    for (int k = 0; k < GSUB; ++k) acc[k] = make_float4(0.f, 0.f, 0.f, 0.f);

    if (j == 0) {
        // src pooling path (1/8 of blocks): prefetch-1 loop, wave-uniform flushes
        float4 accs = make_float4(0.f, 0.f, 0.f, 0.f);
        int gprev = (p < cnt) ? sbatch[p] : 0;
        int i = p;
        float4 xn = make_float4(0.f, 0.f, 0.f, 0.f);
        if (i < cnt) xn = XL(i);
        for (; i < cnt; i += 4) {
            float4 xv = xn;
            if (i + 4 < cnt) xn = XL(i + 4);
            int g = sbatch[i];                  // wave-uniform
            if (g != gprev) {                   // uniform branch
                float* yr = Y + gprev * 256 + fg * 4;
                atomicAdd(yr + 0, accs.x); atomicAdd(yr + 1, accs.y);
                atomicAdd(yr + 2, accs.z); atomicAdd(yr + 3, accs.w);
                accs = make_float4(0.f, 0.f, 0.f, 0.f);
                gprev = g;
            }
            float dg = sdeg[i];
            accs.x = fmaf(dg, xv.x, accs.x); accs.y = fmaf(dg, xv.y, accs.y);
            accs.z = fmaf(dg, xv.z, accs.z); accs.w = fmaf(dg, xv.w, accs.w);
            float4 c0 = sc4[i * 2], c1 = sc4[i * 2 + 1];
            FMA8(c0, c1, xv)
        }
        if (p < cnt) {
            float* yr = Y + gprev * 256 + fg * 4;
            atomicAdd(yr + 0, accs.x); atomicAdd(yr + 1, accs.y);
            atomicAdd(yr + 2, accs.z); atomicAdd(yr + 3, accs.w);
        }
    } else {
        // dst-only path: unroll x4, 4 loads in flight
        int i = p;
        float4 xa, xb, xc, xd;
        if (i      < cnt) xa = XL(i);
        if (i + 4  < cnt) xb = XL(i + 4);
        if (i + 8  < cnt) xc = XL(i + 8);
        if (i + 12 < cnt) xd = XL(i + 12);
        for (; i + 12 < cnt; i += 16) {
            float4 y0 = xa, y1 = xb, y2 = xc, y3 = xd;
            if (i + 16 < cnt) xa = XL(i + 16);
            if (i + 20 < cnt) xb = XL(i + 20);
            if (i + 24 < cnt) xc = XL(i + 24);
            if (i + 28 < cnt) xd = XL(i + 28);
            {
                float4 c0 = sc4[i * 2], c1 = sc4[i * 2 + 1];
                FMA8(c0, c1, y0)
            }
            {
                float4 c0 = sc4[(i + 4) * 2], c1 = sc4[(i + 4) * 2 + 1];
                FMA8(c0, c1, y1)
            }
            {
                float4 c0 = sc4[(i + 8) * 2], c1 = sc4[(i + 8) * 2 + 1];
                FMA8(c0, c1, y2)
            }
            {
                float4 c0 = sc4[(i + 12) * 2], c1 = sc4[(i + 12) * 2 + 1];
                FMA8(c0, c1, y3)
            }
        }
        for (; i < cnt; i += 4) {
            float4 xv = XL(i);
            float4 c0 = sc4[i * 2], c1 = sc4[i * 2 + 1];
            FMA8(c0, c1, xv)
        }
    }
#undef XL

    // cross-phase reduce 4 -> 2 -> 1 (lane-consecutive, conflict-free)
    if (p >= 2) {
#pragma unroll
        for (int k = 0; k < GSUB; ++k) red[(p - 2) * (GSUB * 64) + k * 64 + fg] = acc[k];
    }
    __syncthreads();
    if (p < 2) {
#pragma unroll
        for (int k = 0; k < GSUB; ++k) {
            float4 v = red[p * (GSUB * 64) + k * 64 + fg];
            acc[k].x += v.x; acc[k].y += v.y; acc[k].z += v.z; acc[k].w += v.w;
        }
    }
    __syncthreads();
    if (p == 1) {
#pragma unroll
        for (int k = 0; k < GSUB; ++k) red[k * 64 + fg] = acc[k];
    }
    __syncthreads();
    if (p == 0) {
        float4* part4 = (float4*)part;
#pragma unroll
        for (int k = 0; k < GSUB; ++k) {
            float4 v = red[k * 64 + fg];
            acc[k].x += v.x; acc[k].y += v.y; acc[k].z += v.z; acc[k].w += v.w;
            part4[(size_t)(b * 64 + j * GSUB + k) * 64 + fg] = acc[k];
        }
    }
}

// fused reduce + chain (r3 verbatim): 128 blocks x 256 threads, split-k.
__global__ __launch_bounds__(256) void chain2_k(const float* __restrict__ Y,
                                                const float* __restrict__ part,
                                                const float* __restrict__ counts,
                                                const float* __restrict__ W0, const float* __restrict__ b0,
                                                const float* __restrict__ W1, const float* __restrict__ b1,
                                                const float* __restrict__ W2, const float* __restrict__ b2,
                                                float* __restrict__ out) {
    __shared__ float m[256];
    __shared__ float pp[256];   // split-k partials
    __shared__ float h[128];
    const int r = blockIdx.x;
    const int t = threadIdx.x;
    const int g = r & 63;
    const int half = (r >= 64) ? 128 : 0;
    const int tt = t & 127;
    const int ks = t >> 7;      // k-split id: 0 or 1

    float c = counts[g];
    float inv = 1.0f / fmaxf(c, 1.0f);
    float beta = c * inv;

    if (r < 64) {
        m[t] = Y[g * 256 + t] * inv;
    } else {
        float s = 0.0f;
#pragma unroll 8
        for (int bb = 0; bb < NCHUNK; ++bb) s += part[(size_t)(bb * 64 + g) * 256 + t];
        m[t] = s * inv;
    }
    __syncthreads();

    // layer 1: m(256) @ W0(256x128) -> 128, k split 128/128
    {
        float s = 0.0f;
        const float* w = W0 + (ks * 128) * 128 + tt;
        const float* mm = m + ks * 128;
#pragma unroll 8
        for (int k = 0; k < 128; ++k) s = fmaf(mm[k], w[k * 128], s);
        pp[t] = s;
    }
    __syncthreads();
    if (t < 128) {
        float s1 = pp[t] + pp[t + 128] + beta * b0[t];
        out[g * 768 + 0 + half + t] = s1;
        h[t] = s1;
    }
    __syncthreads();

    // layer 2: h(128) @ W1(128x128) -> 128, k split 64/64
    {
        float s = 0.0f;
        const float* w = W1 + (ks * 64) * 128 + tt;
        const float* hh = h + ks * 64;
#pragma unroll 8
        for (int k = 0; k < 64; ++k) s = fmaf(hh[k], w[k * 128], s);
        pp[t] = s;
    }
    __syncthreads();
    float s2 = 0.0f;
    if (t < 128) {
        s2 = pp[t] + pp[t + 128] + beta * b1[t];
        out[g * 768 + 256 + half + t] = s2;
    }
    __syncthreads();
    if (t < 128) h[t] = s2;
    __syncthreads();

    // layer 3: h(128) @ W2(128x128) -> 128, k split 64/64
    {
        float s = 0.0f;
        const float* w = W2 + (ks * 64) * 128 + tt;
        const float* hh = h + ks * 64;
#pragma unroll 8
        for (int k = 0; k < 64; ++k) s = fmaf(hh[k], w[k * 128], s);
        pp[t] = s;
    }
    __syncthreads();
    if (t < 128) {
        float s3 = pp[t] + pp[t + 128] + beta * b2[t];
        out[g * 768 + 512 + half + t] = s3;
    }
}

extern "C" void kernel_launch(void* const* d_in, const int* in_sizes, int n_in,
                              void* d_out, int out_size, void* d_ws, size_t ws_size,
                              hipStream_t stream) {
    const float* x     = (const float*)d_in[0];
    const int*   ei    = (const int*)d_in[1];
    const int*   batch = (const int*)d_in[2];
    const float* W0    = (const float*)d_in[3];
    const float* b0    = (const float*)d_in[4];
    const float* W1    = (const float*)d_in[5];
    const float* b1    = (const float*)d_in[6];
    const float* W2    = (const float*)d_in[7];
    const float* b2    = (const float*)d_in[8];
    float* out = (float*)d_out;

    float*    ws     = (float*)d_ws;
    float*    Cdcol  = ws + CD_OFF;
    float*    deg    = ws + DEG_OFF;
    float*    counts = ws + CNT_OFF;
    float*    Y      = ws + Y_OFF;
    float*    part   = ws + PART_OFF;
    unsigned* bh     = (unsigned*)(ws + BH_OFF);
    unsigned* vals   = (unsigned*)(ws + VALS_OFF);
    unsigned* glo    = (unsigned*)(ws + GLO_OFF);

    bucket_g_k<<<NBG + 1, 512, 0, stream>>>(ei, batch, vals, bh, Y, glo);
    cd_col_k<<<128, 1024, 0, stream>>>(vals, bh, glo, Cdcol, deg, counts);
    pool_k<<<NCHUNK * GSPLIT, 256, 0, stream>>>(x, batch, Cdcol, deg, Y, part);
    chain2_k<<<128, 256, 0, stream>>>(Y, part, counts, W0, b0, W1, b1, W2, b2, out);
}

// Round 8
// 118.233 us; speedup vs baseline: 2.7375x; 1.0146x over previous
//
#include <hip/hip_runtime.h>

#define N_NODES 20000
#define N_EDGES 640000
#define N_GRAPHS 64

// pool tiling: GSPLIT=4 (16 graphs per block) halves x L2 re-reads vs GSPLIT=8
#define NCHUNK 128
#define CHUNK_SZ 157   // 128*157 = 20096 >= 20000
#define GSPLIT 4
#define GSUB 16

// graph-bucket sort (r3-proven geometry)
#define BG_TILE 2048
#define NBG 313        // ceil(640000/2048)
#define SEGCAP 80
#define GR_CAP 768
#define NSLOT4 (NBG * SEGCAP / 4)   // 6260 uint4 per graph

// ws layout (4B units), ws_size = 256 MiB:
//   Cdcol  [64][20000] f32     at 0
//   deg    [20000] f32         at 1,280,000
//   counts [64] f32            at 1,300,000
//   Y      [64][256] f32       at 1,300,064  (zeroed by bucket tail block)
//   part   [128][64][256] f32  at 1,316,448
//   bh     [313][64] u32       at 3,413,600
//   vals   [64][313][80] u32   at 3,433,632  (ends 5,036,192)
//   glo    [65] u32            at 5,036,192  graph node-range bounds
#define CD_OFF      0
#define DEG_OFF     1280000
#define CNT_OFF     1300000
#define Y_OFF       1300064
#define PART_OFF    1316448
#define BH_OFF      3413600
#define VALS_OFF    3433632
#define GLO_OFF     5036192

// bucket edges by g = batch[src] (r7 verbatim). Tail block does the 65
// graph-range binary searches in parallel + Y zero, off the critical path.
__global__ __launch_bounds__(512) void bucket_g_k(const int* __restrict__ ei,
                                                  const int* __restrict__ batch,
                                                  unsigned* __restrict__ vals,
                                                  unsigned* __restrict__ bh,
                                                  float* __restrict__ Y,
                                                  unsigned* __restrict__ glo) {
    __shared__ unsigned hist[N_GRAPHS];
    __shared__ unsigned base[N_GRAPHS + 1];
    __shared__ unsigned lv[BG_TILE];          // 8 KB reorder tile
    __shared__ unsigned char gidx[BG_TILE];   // 2 KB: output index -> graph
    const int t = threadIdx.x;
    const int blk = blockIdx.x;

    if (blk == NBG) {                          // tail block: glo + Y zero
        if (t < N_GRAPHS + 1) {                // 65 parallel binary searches
            int lo = 0, hi = N_NODES;
            while (lo < hi) { int m = (lo + hi) >> 1; if (batch[m] < t) lo = m + 1; else hi = m; }
            glo[t] = (unsigned)lo;
        }
        float4* y4 = (float4*)Y;
        for (int i = t; i < 64 * 64; i += 512) y4[i] = make_float4(0.f, 0.f, 0.f, 0.f);
        return;
    }

    if (t < N_GRAPHS) hist[t] = 0u;
    __syncthreads();

    const int e0 = blk * BG_TILE;
    const int ecnt = (e0 + BG_TILE <= N_EDGES) ? BG_TILE : (N_EDGES - e0);
    unsigned pv[4], rnk[4], gg[4];
#pragma unroll
    for (int k = 0; k < 4; ++k) {
        int i = t + k * 512;
        if (i < ecnt) {
            unsigned s = (unsigned)ei[e0 + i];
            unsigned d = (unsigned)ei[N_EDGES + e0 + i];
            unsigned g = (unsigned)batch[s];
            pv[k] = (s << 15) | d;
            gg[k] = g;
            rnk[k] = atomicAdd(&hist[g], 1u);
        } else {
            gg[k] = 0xFFFFFFFFu;
        }
    }
    __syncthreads();
    if (t < N_GRAPHS) {                        // wave-0 shfl exclusive scan
        unsigned v = hist[t];
        unsigned sum = v;
#pragma unroll
        for (int off = 1; off < 64; off <<= 1) {
            unsigned u = __shfl_up(sum, off, 64);
            if (t >= off) sum += u;
        }
        base[t + 1] = sum;
        if (t == 0) base[0] = 0u;
        bh[blk * N_GRAPHS + t] = (v > SEGCAP) ? SEGCAP : v;
    }
    __syncthreads();
    if (t < N_GRAPHS) {                        // fill gidx runs
        unsigned b0_ = base[t], b1_ = base[t + 1];
        for (unsigned i = b0_; i < b1_; ++i) gidx[i] = (unsigned char)t;
    }
#pragma unroll
    for (int k = 0; k < 4; ++k) {
        if (gg[k] != 0xFFFFFFFFu) lv[base[gg[k]] + rnk[k]] = pv[k];
    }
    __syncthreads();
    for (int i = t; i < ecnt; i += 512) {      // coalesced per-g runs
        unsigned g = gidx[i];
        unsigned slot = (unsigned)i - base[g];
        if (slot < SEGCAP)
            vals[((size_t)g * NBG + blk) * SEGCAP + slot] = lv[i];
    }
}

// cd (r7 verbatim): 128 blocks = (dst-half, graph), 1024 threads, 20 KB hist.
__global__ __launch_bounds__(1024) void cd_col_k(const unsigned* __restrict__ vals,
                                                 const unsigned* __restrict__ bh,
                                                 const unsigned* __restrict__ glo,
                                                 float* __restrict__ Cdcol,
                                                 float* __restrict__ deg,
                                                 float* __restrict__ counts) {
    __shared__ unsigned scnt[NBG];
    __shared__ unsigned dh[5000];          // 20 KB: 10000 dst bins, u16 halves
    __shared__ unsigned sdeg[GR_CAP];      // 3 KB (h==1 only)
    __shared__ unsigned rc[16];
    const int t = threadIdx.x;
    const int g = blockIdx.x & 63;
    const int h = blockIdx.x >> 6;
    const int dbase = h * 10000;

    for (int i = t; i < 5000; i += 1024) dh[i] = 0u;
    if (h) { if (t < GR_CAP) sdeg[t] = 0u; }
    if (t < NBG) scnt[t] = bh[t * N_GRAPHS + g];
    __syncthreads();
    const int lo = (int)glo[g];
    const int hi = (int)glo[g + 1];

    const uint4* v4 = (const uint4*)(vals + (size_t)g * NBG * SEGCAP);
    for (int i = t; i < NSLOT4; i += 1024) {
        uint4 v = *(v4 + i);
        unsigned w = (unsigned)i * 4u;
        unsigned seg = (unsigned)(((unsigned long long)w * 53687092ull) >> 32);  // w/80 exact
        unsigned local = w - seg * 80u;
        unsigned c = scnt[seg];
#define CD_ONE(VX, L)                                                            \
        if ((L) < c) {                                                           \
            int rd_ = (int)((VX) & 0x7FFFu) - dbase;                             \
            if ((unsigned)rd_ < 10000u)                                          \
                atomicAdd(&dh[rd_ >> 1], 1u << ((rd_ & 1) * 16));                \
            if (h) {                                                             \
                int rs_ = (int)((VX) >> 15) - lo;                                \
                if ((unsigned)rs_ < (unsigned)GR_CAP) atomicAdd(&sdeg[rs_], 1u); \
            }                                                                    \
        }
        CD_ONE(v.x, local + 0u)
        CD_ONE(v.y, local + 1u)
        CD_ONE(v.z, local + 2u)
        CD_ONE(v.w, local + 3u)
#undef CD_ONE
    }
    __syncthreads();

    float2* outc = (float2*)(Cdcol + (size_t)g * N_NODES + dbase);
    for (int w = t; w < 5000; w += 1024) {
        unsigned v = dh[w];
        outc[w] = make_float2((float)(v & 0xFFFFu), (float)(v >> 16));
    }
    if (h) {
        const int range = hi - lo;
        for (int i = t; i < range; i += 1024) deg[lo + i] = (float)sdeg[i];
    } else {
        unsigned s = 0;                        // counts[g]: parallel reduce
        for (int i = t; i < NBG; i += 1024) s += scnt[i];
#pragma unroll
        for (int off = 32; off; off >>= 1) s += __shfl_down(s, off, 64);
        if ((t & 63) == 0) rc[t >> 6] = s;
        __syncthreads();
        if (t == 0) {
            unsigned tot = 0;
#pragma unroll
            for (int i = 0; i < 16; ++i) tot += rc[i];
            counts[g] = (float)tot;
        }
    }
}

// 8 accumulators (ACC+0..ACC+7) updated from c-pair (C0,C1)
#define FMA8X(ACC, C0, C1, XV)                                          \
    acc[ACC+0].x = fmaf(C0.x, XV.x, acc[ACC+0].x); acc[ACC+0].y = fmaf(C0.x, XV.y, acc[ACC+0].y); \
    acc[ACC+0].z = fmaf(C0.x, XV.z, acc[ACC+0].z); acc[ACC+0].w = fmaf(C0.x, XV.w, acc[ACC+0].w); \
    acc[ACC+1].x = fmaf(C0.y, XV.x, acc[ACC+1].x); acc[ACC+1].y = fmaf(C0.y, XV.y, acc[ACC+1].y); \
    acc[ACC+1].z = fmaf(C0.y, XV.z, acc[ACC+1].z); acc[ACC+1].w = fmaf(C0.y, XV.w, acc[ACC+1].w); \
    acc[ACC+2].x = fmaf(C0.z, XV.x, acc[ACC+2].x); acc[ACC+2].y = fmaf(C0.z, XV.y, acc[ACC+2].y); \
    acc[ACC+2].z = fmaf(C0.z, XV.z, acc[ACC+2].z); acc[ACC+2].w = fmaf(C0.z, XV.w, acc[ACC+2].w); \
    acc[ACC+3].x = fmaf(C0.w, XV.x, acc[ACC+3].x); acc[ACC+3].y = fmaf(C0.w, XV.y, acc[ACC+3].y); \
    acc[ACC+3].z = fmaf(C0.w, XV.z, acc[ACC+3].z); acc[ACC+3].w = fmaf(C0.w, XV.w, acc[ACC+3].w); \
    acc[ACC+4].x = fmaf(C1.x, XV.x, acc[ACC+4].x); acc[ACC+4].y = fmaf(C1.x, XV.y, acc[ACC+4].y); \
    acc[ACC+4].z = fmaf(C1.x, XV.z, acc[ACC+4].z); acc[ACC+4].w = fmaf(C1.x, XV.w, acc[ACC+4].w); \
    acc[ACC+5].x = fmaf(C1.y, XV.x, acc[ACC+5].x); acc[ACC+5].y = fmaf(C1.y, XV.y, acc[ACC+5].y); \
    acc[ACC+5].z = fmaf(C1.y, XV.z, acc[ACC+5].z); acc[ACC+5].w = fmaf(C1.y, XV.w, acc[ACC+5].w); \
    acc[ACC+6].x = fmaf(C1.z, XV.x, acc[ACC+6].x); acc[ACC+6].y = fmaf(C1.z, XV.y, acc[ACC+6].y); \
    acc[ACC+6].z = fmaf(C1.z, XV.z, acc[ACC+6].z); acc[ACC+6].w = fmaf(C1.z, XV.w, acc[ACC+6].w); \
    acc[ACC+7].x = fmaf(C1.w, XV.x, acc[ACC+7].x); acc[ACC+7].y = fmaf(C1.w, XV.y, acc[ACC+7].y); \
    acc[ACC+7].z = fmaf(C1.w, XV.z, acc[ACC+7].z); acc[ACC+7].w = fmaf(C1.w, XV.w, acc[ACC+7].w);

#define FMA16(I, XV)                                               \
    { float4 c0_ = sc4[(I) * 4], c1_ = sc4[(I) * 4 + 1];           \
      float4 c2_ = sc4[(I) * 4 + 2], c3_ = sc4[(I) * 4 + 3];       \
      FMA8X(0, c0_, c1_, XV)                                       \
      FMA8X(8, c2_, c3_, XV) }

// pool v3: block = (chunk b, split j of 4); 16 graphs/block -> x fetched 4x
// (was 8x) from L2. Same wave-striping, 4-deep prefetch, and (p0+p2)+(p1+p3)
// reduce tree as r3 -> part is bit-identical.
__global__ __launch_bounds__(256) void pool_k(const float* __restrict__ x,
                                              const int* __restrict__ batch,
                                              const float* __restrict__ Cdcol,
                                              const float* __restrict__ deg,
                                              float* __restrict__ Y,
                                              float* __restrict__ part) {
    __shared__ float4 sc4[CHUNK_SZ * 4];      // 10 KB: [node][4] float4 (GSUB=16)
    __shared__ float sdeg[CHUNK_SZ];
    __shared__ int   sbatch[CHUNK_SZ];
    __shared__ float4 red[2 * GSUB * 64];     // 32 KB cross-phase reduce

    const int t = threadIdx.x;
    const int fg = t & 63;                    // float4 feature group
    const int p  = t >> 6;                    // phase == wave id
    const int b = blockIdx.x & 127;           // same chunk's 4 splits: same XCD mod 8
    const int j = blockIdx.x >> 7;            // 0..3
    const int n0 = b * CHUNK_SZ;
    const int cnt = (n0 + CHUNK_SZ <= N_NODES) ? CHUNK_SZ : (N_NODES - n0);

    // transpose-stage 16 Cd columns into [node][16] LDS layout
    float* sc = (float*)sc4;
    const float* cbase = Cdcol + (size_t)(j * GSUB) * N_NODES + n0;
#pragma unroll
    for (int k = 0; k < GSUB; ++k)
        for (int i = t; i < cnt; i += 256)
            sc[i * GSUB + k] = cbase[(size_t)k * N_NODES + i];
    if (j == 0) {
        for (int i = t; i < cnt; i += 256) {
            sdeg[i] = deg[n0 + i];
            sbatch[i] = batch[n0 + i];
        }
    }
    __syncthreads();

    const float4* xp = (const float4*)x + (size_t)n0 * 64 + fg;
#define XL(I) xp[(size_t)(I) * 64]
    float4 acc[GSUB];
#pragma unroll
    for (int k = 0; k < GSUB; ++k) acc[k] = make_float4(0.f, 0.f, 0.f, 0.f);

    if (j == 0) {
        // src pooling path (1/4 of blocks): prefetch-1 loop, wave-uniform flushes
        float4 accs = make_float4(0.f, 0.f, 0.f, 0.f);
        int gprev = (p < cnt) ? sbatch[p] : 0;
        int i = p;
        float4 xn = make_float4(0.f, 0.f, 0.f, 0.f);
        if (i < cnt) xn = XL(i);
        for (; i < cnt; i += 4) {
            float4 xv = xn;
            if (i + 4 < cnt) xn = XL(i + 4);
            int g = sbatch[i];                  // wave-uniform
            if (g != gprev) {                   // uniform branch
                float* yr = Y + gprev * 256 + fg * 4;
                atomicAdd(yr + 0, accs.x); atomicAdd(yr + 1, accs.y);
                atomicAdd(yr + 2, accs.z); atomicAdd(yr + 3, accs.w);
                accs = make_float4(0.f, 0.f, 0.f, 0.f);
                gprev = g;
            }
            float dg = sdeg[i];
            accs.x = fmaf(dg, xv.x, accs.x); accs.y = fmaf(dg, xv.y, accs.y);
            accs.z = fmaf(dg, xv.z, accs.z); accs.w = fmaf(dg, xv.w, accs.w);
            FMA16(i, xv)
        }
        if (p < cnt) {
            float* yr = Y + gprev * 256 + fg * 4;
            atomicAdd(yr + 0, accs.x); atomicAdd(yr + 1, accs.y);
            atomicAdd(yr + 2, accs.z); atomicAdd(yr + 3, accs.w);
        }
    } else {
        // dst-only path: unroll x4, 4 loads in flight
        int i = p;
        float4 xa, xb, xc, xd;
        if (i      < cnt) xa = XL(i);
        if (i + 4  < cnt) xb = XL(i + 4);
        if (i + 8  < cnt) xc = XL(i + 8);
        if (i + 12 < cnt) xd = XL(i + 12);
        for (; i + 12 < cnt; i += 16) {
            float4 y0 = xa, y1 = xb, y2 = xc, y3 = xd;
            if (i + 16 < cnt) xa = XL(i + 16);
            if (i + 20 < cnt) xb = XL(i + 20);
            if (i + 24 < cnt) xc = XL(i + 24);
            if (i + 28 < cnt) xd = XL(i + 28);
            FMA16(i, y0)
            FMA16(i + 4, y1)
            FMA16(i + 8, y2)
            FMA16(i + 12, y3)
        }
        for (; i < cnt; i += 4) {
            float4 xv = XL(i);
            FMA16(i, xv)
        }
    }
#undef XL

    // cross-phase reduce 4 -> 2 -> 1 (same tree as r3: (p0+p2)+(p1+p3))
    if (p >= 2) {
#pragma unroll
        for (int k = 0; k < GSUB; ++k) red[(p - 2) * (GSUB * 64) + k * 64 + fg] = acc[k];
    }
    __syncthreads();
    if (p < 2) {
#pragma unroll
        for (int k = 0; k < GSUB; ++k) {
            float4 v = red[p * (GSUB * 64) + k * 64 + fg];
            acc[k].x += v.x; acc[k].y += v.y; acc[k].z += v.z; acc[k].w += v.w;
        }
    }
    __syncthreads();
    if (p == 1) {
#pragma unroll
        for (int k = 0; k < GSUB; ++k) red[k * 64 + fg] = acc[k];
    }
    __syncthreads();
    if (p == 0) {
        float4* part4 = (float4*)part;
#pragma unroll
        for (int k = 0; k < GSUB; ++k) {
            float4 v = red[k * 64 + fg];
            acc[k].x += v.x; acc[k].y += v.y; acc[k].z += v.z; acc[k].w += v.w;
            part4[(size_t)(b * 64 + j * GSUB + k) * 64 + fg] = acc[k];
        }
    }
}

// fused reduce + chain (r7 verbatim): 128 blocks x 256 threads, split-k.
__global__ __launch_bounds__(256) void chain2_k(const float* __restrict__ Y,
                                                const float* __restrict__ part,
                                                const float* __restrict__ counts,
                                                const float* __restrict__ W0, const float* __restrict__ b0,
                                                const float* __restrict__ W1, const float* __restrict__ b1,
                                                const float* __restrict__ W2, const float* __restrict__ b2,
                                                float* __restrict__ out) {
    __shared__ float m[256];
    __shared__ float pp[256];   // split-k partials
    __shared__ float h[128];
    const int r = blockIdx.x;
    const int t = threadIdx.x;
    const int g = r & 63;
    const int half = (r >= 64) ? 128 : 0;
    const int tt = t & 127;
    const int ks = t >> 7;      // k-split id: 0 or 1

    float c = counts[g];
    float inv = 1.0f / fmaxf(c, 1.0f);
    float beta = c * inv;

    if (r < 64) {
        m[t] = Y[g * 256 + t] * inv;
    } else {
        float s = 0.0f;
#pragma unroll 8
        for (int bb = 0; bb < NCHUNK; ++bb) s += part[(size_t)(bb * 64 + g) * 256 + t];
        m[t] = s * inv;
    }
    __syncthreads();

    // layer 1: m(256) @ W0(256x128) -> 128, k split 128/128
    {
        float s = 0.0f;
        const float* w = W0 + (ks * 128) * 128 + tt;
        const float* mm = m + ks * 128;
#pragma unroll 8
        for (int k = 0; k < 128; ++k) s = fmaf(mm[k], w[k * 128], s);
        pp[t] = s;
    }
    __syncthreads();
    if (t < 128) {
        float s1 = pp[t] + pp[t + 128] + beta * b0[t];
        out[g * 768 + 0 + half + t] = s1;
        h[t] = s1;
    }
    __syncthreads();

    // layer 2: h(128) @ W1(128x128) -> 128, k split 64/64
    {
        float s = 0.0f;
        const float* w = W1 + (ks * 64) * 128 + tt;
        const float* hh = h + ks * 64;
#pragma unroll 8
        for (int k = 0; k < 64; ++k) s = fmaf(hh[k], w[k * 128], s);
        pp[t] = s;
    }
    __syncthreads();
    float s2 = 0.0f;
    if (t < 128) {
        s2 = pp[t] + pp[t + 128] + beta * b1[t];
        out[g * 768 + 256 + half + t] = s2;
    }
    __syncthreads();
    if (t < 128) h[t] = s2;
    __syncthreads();

    // layer 3: h(128) @ W2(128x128) -> 128, k split 64/64
    {
        float s = 0.0f;
        const float* w = W2 + (ks * 64) * 128 + tt;
        const float* hh = h + ks * 64;
#pragma unroll 8
        for (int k = 0; k < 64; ++k) s = fmaf(hh[k], w[k * 128], s);
        pp[t] = s;
    }
    __syncthreads();
    if (t < 128) {
        float s3 = pp[t] + pp[t + 128] + beta * b2[t];
        out[g * 768 + 512 + half + t] = s3;
    }
}

extern "C" void kernel_launch(void* const* d_in, const int* in_sizes, int n_in,
                              void* d_out, int out_size, void* d_ws, size_t ws_size,
                              hipStream_t stream) {
    const float* x     = (const float*)d_in[0];
    const int*   ei    = (const int*)d_in[1];
    const int*   batch = (const int*)d_in[2];
    const float* W0    = (const float*)d_in[3];
    const float* b0    = (const float*)d_in[4];
    const float* W1    = (const float*)d_in[5];
    const float* b1    = (const float*)d_in[6];
    const float* W2    = (const float*)d_in[7];
    const float* b2    = (const float*)d_in[8];
    float* out = (float*)d_out;

    float*    ws     = (float*)d_ws;
    float*    Cdcol  = ws + CD_OFF;
    float*    deg    = ws + DEG_OFF;
    float*    counts = ws + CNT_OFF;
    float*    Y      = ws + Y_OFF;
    float*    part   = ws + PART_OFF;
    unsigned* bh     = (unsigned*)(ws + BH_OFF);
    unsigned* vals   = (unsigned*)(ws + VALS_OFF);
    unsigned* glo    = (unsigned*)(ws + GLO_OFF);

    bucket_g_k<<<NBG + 1, 512, 0, stream>>>(ei, batch, vals, bh, Y, glo);
    cd_col_k<<<128, 1024, 0, stream>>>(vals, bh, glo, Cdcol, deg, counts);
    pool_k<<<NCHUNK * GSPLIT, 256, 0, stream>>>(x, batch, Cdcol, deg, Y, part);
    chain2_k<<<128, 256, 0, stream>>>(Y, part, counts, W0, b0, W1, b1, W2, b2, out);
}

// Round 9
// 114.397 us; speedup vs baseline: 2.8294x; 1.0335x over previous
//
#include <hip/hip_runtime.h>

#define N_NODES 20000
#define N_EDGES 640000
#define N_GRAPHS 64

// pool tiling: GSPLIT=4 (16 graphs per block) halves x L2 re-reads vs GSPLIT=8
#define NCHUNK 128
#define CHUNK_SZ 157   // 128*157 = 20096 >= 20000
#define GSPLIT 4
#define GSUB 16

// graph-bucket sort (r3-proven geometry)
#define BG_TILE 2048
#define NBG 313        // ceil(640000/2048)
#define SEGCAP 80
#define GR_CAP 768
#define NSLOT4 (NBG * SEGCAP / 4)   // 6260 uint4 per graph

// ws layout (4B units), ws_size = 256 MiB:
//   Cdcol  [64][20000] f32     at 0
//   deg    [20000] f32         at 1,280,000
//   counts [64] f32            at 1,300,000
//   Y      [64][256] f32       at 1,300,064  (zeroed by bucket tail block)
//   part   [128][64][256] f32  at 1,316,448
//   bh     [313][64] u32       at 3,413,600
//   vals   [64][313][80] u32   at 3,433,632  (ends 5,036,192)
//   glo    [65] u32            at 5,036,192  graph node-range bounds
#define CD_OFF      0
#define DEG_OFF     1280000
#define CNT_OFF     1300000
#define Y_OFF       1300064
#define PART_OFF    1316448
#define BH_OFF      3413600
#define VALS_OFF    3433632
#define GLO_OFF     5036192

// bucket edges by g = batch[src] (r7 verbatim). Tail block does the 65
// graph-range binary searches in parallel + Y zero, off the critical path.
__global__ __launch_bounds__(512) void bucket_g_k(const int* __restrict__ ei,
                                                  const int* __restrict__ batch,
                                                  unsigned* __restrict__ vals,
                                                  unsigned* __restrict__ bh,
                                                  float* __restrict__ Y,
                                                  unsigned* __restrict__ glo) {
    __shared__ unsigned hist[N_GRAPHS];
    __shared__ unsigned base[N_GRAPHS + 1];
    __shared__ unsigned lv[BG_TILE];          // 8 KB reorder tile
    __shared__ unsigned char gidx[BG_TILE];   // 2 KB: output index -> graph
    const int t = threadIdx.x;
    const int blk = blockIdx.x;

    if (blk == NBG) {                          // tail block: glo + Y zero
        if (t < N_GRAPHS + 1) {                // 65 parallel binary searches
            int lo = 0, hi = N_NODES;
            while (lo < hi) { int m = (lo + hi) >> 1; if (batch[m] < t) lo = m + 1; else hi = m; }
            glo[t] = (unsigned)lo;
        }
        float4* y4 = (float4*)Y;
        for (int i = t; i < 64 * 64; i += 512) y4[i] = make_float4(0.f, 0.f, 0.f, 0.f);
        return;
    }

    if (t < N_GRAPHS) hist[t] = 0u;
    __syncthreads();

    const int e0 = blk * BG_TILE;
    const int ecnt = (e0 + BG_TILE <= N_EDGES) ? BG_TILE : (N_EDGES - e0);
    unsigned pv[4], rnk[4], gg[4];
#pragma unroll
    for (int k = 0; k < 4; ++k) {
        int i = t + k * 512;
        if (i < ecnt) {
            unsigned s = (unsigned)ei[e0 + i];
            unsigned d = (unsigned)ei[N_EDGES + e0 + i];
            unsigned g = (unsigned)batch[s];
            pv[k] = (s << 15) | d;
            gg[k] = g;
            rnk[k] = atomicAdd(&hist[g], 1u);
        } else {
            gg[k] = 0xFFFFFFFFu;
        }
    }
    __syncthreads();
    if (t < N_GRAPHS) {                        // wave-0 shfl exclusive scan
        unsigned v = hist[t];
        unsigned sum = v;
#pragma unroll
        for (int off = 1; off < 64; off <<= 1) {
            unsigned u = __shfl_up(sum, off, 64);
            if (t >= off) sum += u;
        }
        base[t + 1] = sum;
        if (t == 0) base[0] = 0u;
        bh[blk * N_GRAPHS + t] = (v > SEGCAP) ? SEGCAP : v;
    }
    __syncthreads();
    if (t < N_GRAPHS) {                        // fill gidx runs
        unsigned b0_ = base[t], b1_ = base[t + 1];
        for (unsigned i = b0_; i < b1_; ++i) gidx[i] = (unsigned char)t;
    }
#pragma unroll
    for (int k = 0; k < 4; ++k) {
        if (gg[k] != 0xFFFFFFFFu) lv[base[gg[k]] + rnk[k]] = pv[k];
    }
    __syncthreads();
    for (int i = t; i < ecnt; i += 512) {      // coalesced per-g runs
        unsigned g = gidx[i];
        unsigned slot = (unsigned)i - base[g];
        if (slot < SEGCAP)
            vals[((size_t)g * NBG + blk) * SEGCAP + slot] = lv[i];
    }
}

// cd (r7 verbatim): 128 blocks = (dst-half, graph), 1024 threads, 20 KB hist.
__global__ __launch_bounds__(1024) void cd_col_k(const unsigned* __restrict__ vals,
                                                 const unsigned* __restrict__ bh,
                                                 const unsigned* __restrict__ glo,
                                                 float* __restrict__ Cdcol,
                                                 float* __restrict__ deg,
                                                 float* __restrict__ counts) {
    __shared__ unsigned scnt[NBG];
    __shared__ unsigned dh[5000];          // 20 KB: 10000 dst bins, u16 halves
    __shared__ unsigned sdeg[GR_CAP];      // 3 KB (h==1 only)
    __shared__ unsigned rc[16];
    const int t = threadIdx.x;
    const int g = blockIdx.x & 63;
    const int h = blockIdx.x >> 6;
    const int dbase = h * 10000;

    for (int i = t; i < 5000; i += 1024) dh[i] = 0u;
    if (h) { if (t < GR_CAP) sdeg[t] = 0u; }
    if (t < NBG) scnt[t] = bh[t * N_GRAPHS + g];
    __syncthreads();
    const int lo = (int)glo[g];
    const int hi = (int)glo[g + 1];

    const uint4* v4 = (const uint4*)(vals + (size_t)g * NBG * SEGCAP);
    for (int i = t; i < NSLOT4; i += 1024) {
        uint4 v = *(v4 + i);
        unsigned w = (unsigned)i * 4u;
        unsigned seg = (unsigned)(((unsigned long long)w * 53687092ull) >> 32);  // w/80 exact
        unsigned local = w - seg * 80u;
        unsigned c = scnt[seg];
#define CD_ONE(VX, L)                                                            \
        if ((L) < c) {                                                           \
            int rd_ = (int)((VX) & 0x7FFFu) - dbase;                             \
            if ((unsigned)rd_ < 10000u)                                          \
                atomicAdd(&dh[rd_ >> 1], 1u << ((rd_ & 1) * 16));                \
            if (h) {                                                             \
                int rs_ = (int)((VX) >> 15) - lo;                                \
                if ((unsigned)rs_ < (unsigned)GR_CAP) atomicAdd(&sdeg[rs_], 1u); \
            }                                                                    \
        }
        CD_ONE(v.x, local + 0u)
        CD_ONE(v.y, local + 1u)
        CD_ONE(v.z, local + 2u)
        CD_ONE(v.w, local + 3u)
#undef CD_ONE
    }
    __syncthreads();

    float2* outc = (float2*)(Cdcol + (size_t)g * N_NODES + dbase);
    for (int w = t; w < 5000; w += 1024) {
        unsigned v = dh[w];
        outc[w] = make_float2((float)(v & 0xFFFFu), (float)(v >> 16));
    }
    if (h) {
        const int range = hi - lo;
        for (int i = t; i < range; i += 1024) deg[lo + i] = (float)sdeg[i];
    } else {
        unsigned s = 0;                        // counts[g]: parallel reduce
        for (int i = t; i < NBG; i += 1024) s += scnt[i];
#pragma unroll
        for (int off = 32; off; off >>= 1) s += __shfl_down(s, off, 64);
        if ((t & 63) == 0) rc[t >> 6] = s;
        __syncthreads();
        if (t == 0) {
            unsigned tot = 0;
#pragma unroll
            for (int i = 0; i < 16; ++i) tot += rc[i];
            counts[g] = (float)tot;
        }
    }
}

// 8 accumulators (ACC+0..ACC+7) updated from c-pair (C0,C1)
#define FMA8X(ACC, C0, C1, XV)                                          \
    acc[ACC+0].x = fmaf(C0.x, XV.x, acc[ACC+0].x); acc[ACC+0].y = fmaf(C0.x, XV.y, acc[ACC+0].y); \
    acc[ACC+0].z = fmaf(C0.x, XV.z, acc[ACC+0].z); acc[ACC+0].w = fmaf(C0.x, XV.w, acc[ACC+0].w); \
    acc[ACC+1].x = fmaf(C0.y, XV.x, acc[ACC+1].x); acc[ACC+1].y = fmaf(C0.y, XV.y, acc[ACC+1].y); \
    acc[ACC+1].z = fmaf(C0.y, XV.z, acc[ACC+1].z); acc[ACC+1].w = fmaf(C0.y, XV.w, acc[ACC+1].w); \
    acc[ACC+2].x = fmaf(C0.z, XV.x, acc[ACC+2].x); acc[ACC+2].y = fmaf(C0.z, XV.y, acc[ACC+2].y); \
    acc[ACC+2].z = fmaf(C0.z, XV.z, acc[ACC+2].z); acc[ACC+2].w = fmaf(C0.z, XV.w, acc[ACC+2].w); \
    acc[ACC+3].x = fmaf(C0.w, XV.x, acc[ACC+3].x); acc[ACC+3].y = fmaf(C0.w, XV.y, acc[ACC+3].y); \
    acc[ACC+3].z = fmaf(C0.w, XV.z, acc[ACC+3].z); acc[ACC+3].w = fmaf(C0.w, XV.w, acc[ACC+3].w); \
    acc[ACC+4].x = fmaf(C1.x, XV.x, acc[ACC+4].x); acc[ACC+4].y = fmaf(C1.x, XV.y, acc[ACC+4].y); \
    acc[ACC+4].z = fmaf(C1.x, XV.z, acc[ACC+4].z); acc[ACC+4].w = fmaf(C1.x, XV.w, acc[ACC+4].w); \
    acc[ACC+5].x = fmaf(C1.y, XV.x, acc[ACC+5].x); acc[ACC+5].y = fmaf(C1.y, XV.y, acc[ACC+5].y); \
    acc[ACC+5].z = fmaf(C1.y, XV.z, acc[ACC+5].z); acc[ACC+5].w = fmaf(C1.y, XV.w, acc[ACC+5].w); \
    acc[ACC+6].x = fmaf(C1.z, XV.x, acc[ACC+6].x); acc[ACC+6].y = fmaf(C1.z, XV.y, acc[ACC+6].y); \
    acc[ACC+6].z = fmaf(C1.z, XV.z, acc[ACC+6].z); acc[ACC+6].w = fmaf(C1.z, XV.w, acc[ACC+6].w); \
    acc[ACC+7].x = fmaf(C1.w, XV.x, acc[ACC+7].x); acc[ACC+7].y = fmaf(C1.w, XV.y, acc[ACC+7].y); \
    acc[ACC+7].z = fmaf(C1.w, XV.z, acc[ACC+7].z); acc[ACC+7].w = fmaf(C1.w, XV.w, acc[ACC+7].w);

#define FMA16(I, XV)                                               \
    { float4 c0_ = sc4[(I) * 4], c1_ = sc4[(I) * 4 + 1];           \
      float4 c2_ = sc4[(I) * 4 + 2], c3_ = sc4[(I) * 4 + 3];       \
      FMA8X(0, c0_, c1_, XV)                                       \
      FMA8X(8, c2_, c3_, XV) }

// pool (r8 verbatim): block = (chunk b, split j of 4); 16 graphs/block.
__global__ __launch_bounds__(256) void pool_k(const float* __restrict__ x,
                                              const int* __restrict__ batch,
                                              const float* __restrict__ Cdcol,
                                              const float* __restrict__ deg,
                                              float* __restrict__ Y,
                                              float* __restrict__ part) {
    __shared__ float4 sc4[CHUNK_SZ * 4];      // 10 KB: [node][4] float4 (GSUB=16)
    __shared__ float sdeg[CHUNK_SZ];
    __shared__ int   sbatch[CHUNK_SZ];
    __shared__ float4 red[2 * GSUB * 64];     // 32 KB cross-phase reduce

    const int t = threadIdx.x;
    const int fg = t & 63;                    // float4 feature group
    const int p  = t >> 6;                    // phase == wave id
    const int b = blockIdx.x & 127;           // same chunk's 4 splits: same XCD mod 8
    const int j = blockIdx.x >> 7;            // 0..3
    const int n0 = b * CHUNK_SZ;
    const int cnt = (n0 + CHUNK_SZ <= N_NODES) ? CHUNK_SZ : (N_NODES - n0);

    // transpose-stage 16 Cd columns into [node][16] LDS layout
    float* sc = (float*)sc4;
    const float* cbase = Cdcol + (size_t)(j * GSUB) * N_NODES + n0;
#pragma unroll
    for (int k = 0; k < GSUB; ++k)
        for (int i = t; i < cnt; i += 256)
            sc[i * GSUB + k] = cbase[(size_t)k * N_NODES + i];
    if (j == 0) {
        for (int i = t; i < cnt; i += 256) {
            sdeg[i] = deg[n0 + i];
            sbatch[i] = batch[n0 + i];
        }
    }
    __syncthreads();

    const float4* xp = (const float4*)x + (size_t)n0 * 64 + fg;
#define XL(I) xp[(size_t)(I) * 64]
    float4 acc[GSUB];
#pragma unroll
    for (int k = 0; k < GSUB; ++k) acc[k] = make_float4(0.f, 0.f, 0.f, 0.f);

    if (j == 0) {
        // src pooling path (1/4 of blocks): prefetch-1 loop, wave-uniform flushes
        float4 accs = make_float4(0.f, 0.f, 0.f, 0.f);
        int gprev = (p < cnt) ? sbatch[p] : 0;
        int i = p;
        float4 xn = make_float4(0.f, 0.f, 0.f, 0.f);
        if (i < cnt) xn = XL(i);
        for (; i < cnt; i += 4) {
            float4 xv = xn;
            if (i + 4 < cnt) xn = XL(i + 4);
            int g = sbatch[i];                  // wave-uniform
            if (g != gprev) {                   // uniform branch
                float* yr = Y + gprev * 256 + fg * 4;
                atomicAdd(yr + 0, accs.x); atomicAdd(yr + 1, accs.y);
                atomicAdd(yr + 2, accs.z); atomicAdd(yr + 3, accs.w);
                accs = make_float4(0.f, 0.f, 0.f, 0.f);
                gprev = g;
            }
            float dg = sdeg[i];
            accs.x = fmaf(dg, xv.x, accs.x); accs.y = fmaf(dg, xv.y, accs.y);
            accs.z = fmaf(dg, xv.z, accs.z); accs.w = fmaf(dg, xv.w, accs.w);
            FMA16(i, xv)
        }
        if (p < cnt) {
            float* yr = Y + gprev * 256 + fg * 4;
            atomicAdd(yr + 0, accs.x); atomicAdd(yr + 1, accs.y);
            atomicAdd(yr + 2, accs.z); atomicAdd(yr + 3, accs.w);
        }
    } else {
        // dst-only path: unroll x4, 4 loads in flight
        int i = p;
        float4 xa, xb, xc, xd;
        if (i      < cnt) xa = XL(i);
        if (i + 4  < cnt) xb = XL(i + 4);
        if (i + 8  < cnt) xc = XL(i + 8);
        if (i + 12 < cnt) xd = XL(i + 12);
        for (; i + 12 < cnt; i += 16) {
            float4 y0 = xa, y1 = xb, y2 = xc, y3 = xd;
            if (i + 16 < cnt) xa = XL(i + 16);
            if (i + 20 < cnt) xb = XL(i + 20);
            if (i + 24 < cnt) xc = XL(i + 24);
            if (i + 28 < cnt) xd = XL(i + 28);
            FMA16(i, y0)
            FMA16(i + 4, y1)
            FMA16(i + 8, y2)
            FMA16(i + 12, y3)
        }
        for (; i < cnt; i += 4) {
            float4 xv = XL(i);
            FMA16(i, xv)
        }
    }
#undef XL

    // cross-phase reduce 4 -> 2 -> 1 (same tree as r3: (p0+p2)+(p1+p3))
    if (p >= 2) {
#pragma unroll
        for (int k = 0; k < GSUB; ++k) red[(p - 2) * (GSUB * 64) + k * 64 + fg] = acc[k];
    }
    __syncthreads();
    if (p < 2) {
#pragma unroll
        for (int k = 0; k < GSUB; ++k) {
            float4 v = red[p * (GSUB * 64) + k * 64 + fg];
            acc[k].x += v.x; acc[k].y += v.y; acc[k].z += v.z; acc[k].w += v.w;
        }
    }
    __syncthreads();
    if (p == 1) {
#pragma unroll
        for (int k = 0; k < GSUB; ++k) red[k * 64 + fg] = acc[k];
    }
    __syncthreads();
    if (p == 0) {
        float4* part4 = (float4*)part;
#pragma unroll
        for (int k = 0; k < GSUB; ++k) {
            float4 v = red[k * 64 + fg];
            acc[k].x += v.x; acc[k].y += v.y; acc[k].z += v.z; acc[k].w += v.w;
            part4[(size_t)(b * 64 + j * GSUB + k) * 64 + fg] = acc[k];
        }
    }
}

// chain v3: 128 blocks x 512 threads. Slab-split part-reduce (sk = t>>8 owns
// 64 of the 128 slabs, unroll 16 -> ~4 latency rounds instead of ~16) and
// 4-way split-k in every layer (ks = t>>7). Math identical up to summation
// order (pairwise combines) -> absmax within tolerance.
__global__ __launch_bounds__(512) void chain2_k(const float* __restrict__ Y,
                                                const float* __restrict__ part,
                                                const float* __restrict__ counts,
                                                const float* __restrict__ W0, const float* __restrict__ b0,
                                                const float* __restrict__ W1, const float* __restrict__ b1,
                                                const float* __restrict__ W2, const float* __restrict__ b2,
                                                float* __restrict__ out) {
    __shared__ float m[256];
    __shared__ float pp[512];   // split partials (slab halves / k-quarters)
    __shared__ float h[128];
    const int r = blockIdx.x;
    const int t = threadIdx.x;
    const int g = r & 63;
    const int half = (r >= 64) ? 128 : 0;
    const int t256 = t & 255;   // feature for part-reduce
    const int sk = t >> 8;      // slab half 0/1
    const int tt = t & 127;     // layer output feature
    const int ks = t >> 7;      // k-split id 0..3

    float c = counts[g];
    float inv = 1.0f / fmaxf(c, 1.0f);
    float beta = c * inv;

    if (r < 64) {
        if (t < 256) m[t] = Y[g * 256 + t] * inv;
    } else {
        float s = 0.0f;
        const float* pbase = part + ((size_t)(sk * 64) * 64 + g) * 256 + t256;
#pragma unroll 16
        for (int bb = 0; bb < 64; ++bb) s += pbase[(size_t)bb * 64 * 256];
        pp[t] = s;
        __syncthreads();
        if (t < 256) m[t] = (pp[t] + pp[t + 256]) * inv;
    }
    __syncthreads();

    // layer 1: m(256) @ W0(256x128) -> 128, k split 4 x 64
    {
        float s = 0.0f;
        const float* w = W0 + (ks * 64) * 128 + tt;
        const float* mm = m + ks * 64;
#pragma unroll 8
        for (int k = 0; k < 64; ++k) s = fmaf(mm[k], w[k * 128], s);
        pp[t] = s;
    }
    __syncthreads();
    if (t < 128) {
        float s1 = (pp[t] + pp[t + 128]) + (pp[t + 256] + pp[t + 384]) + beta * b0[t];
        out[g * 768 + 0 + half + t] = s1;
        h[t] = s1;
    }
    __syncthreads();

    // layer 2: h(128) @ W1(128x128) -> 128, k split 4 x 32
    {
        float s = 0.0f;
        const float* w = W1 + (ks * 32) * 128 + tt;
        const float* hh = h + ks * 32;
#pragma unroll 8
        for (int k = 0; k < 32; ++k) s = fmaf(hh[k], w[k * 128], s);
        pp[t] = s;
    }
    __syncthreads();
    float s2 = 0.0f;
    if (t < 128) {
        s2 = (pp[t] + pp[t + 128]) + (pp[t + 256] + pp[t + 384]) + beta * b1[t];
        out[g * 768 + 256 + half + t] = s2;
    }
    __syncthreads();
    if (t < 128) h[t] = s2;
    __syncthreads();

    // layer 3: h(128) @ W2(128x128) -> 128, k split 4 x 32
    {
        float s = 0.0f;
        const float* w = W2 + (ks * 32) * 128 + tt;
        const float* hh = h + ks * 32;
#pragma unroll 8
        for (int k = 0; k < 32; ++k) s = fmaf(hh[k], w[k * 128], s);
        pp[t] = s;
    }
    __syncthreads();
    if (t < 128) {
        float s3 = (pp[t] + pp[t + 128]) + (pp[t + 256] + pp[t + 384]) + beta * b2[t];
        out[g * 768 + 512 + half + t] = s3;
    }
}

extern "C" void kernel_launch(void* const* d_in, const int* in_sizes, int n_in,
                              void* d_out, int out_size, void* d_ws, size_t ws_size,
                              hipStream_t stream) {
    const float* x     = (const float*)d_in[0];
    const int*   ei    = (const int*)d_in[1];
    const int*   batch = (const int*)d_in[2];
    const float* W0    = (const float*)d_in[3];
    const float* b0    = (const float*)d_in[4];
    const float* W1    = (const float*)d_in[5];
    const float* b1    = (const float*)d_in[6];
    const float* W2    = (const float*)d_in[7];
    const float* b2    = (const float*)d_in[8];
    float* out = (float*)d_out;

    float*    ws     = (float*)d_ws;
    float*    Cdcol  = ws + CD_OFF;
    float*    deg    = ws + DEG_OFF;
    float*    counts = ws + CNT_OFF;
    float*    Y      = ws + Y_OFF;
    float*    part   = ws + PART_OFF;
    unsigned* bh     = (unsigned*)(ws + BH_OFF);
    unsigned* vals   = (unsigned*)(ws + VALS_OFF);
    unsigned* glo    = (unsigned*)(ws + GLO_OFF);

    bucket_g_k<<<NBG + 1, 512, 0, stream>>>(ei, batch, vals, bh, Y, glo);
    cd_col_k<<<128, 1024, 0, stream>>>(vals, bh, glo, Cdcol, deg, counts);
    pool_k<<<NCHUNK * GSPLIT, 256, 0, stream>>>(x, batch, Cdcol, deg, Y, part);
    chain2_k<<<128, 512, 0, stream>>>(Y, part, counts, W0, b0, W1, b1, W2, b2, out);
}